// Round 3
// baseline (728.701 us; speedup 1.0000x reference)
//
#include <hip/hip_runtime.h>
#include <hip/hip_bf16.h>
#include <stdint.h>

// GraphSAGE 2-layer encoder — CSR-gather pipeline with runtime dtype detection.
//
//   probe    : classify each float input bf16 vs fp32; edge_index int32 vs int64
//   count    : in-degree per dst (int atomics)
//   scan     : exclusive prefix sum over degrees -> CSR offsets
//   fill     : dst-sorted src list (1 int atomic per edge)
//   layer1   : gather-mean x[src] + fused GEMM K=128 -> h (bf16, ours)
//   layer2   : gather-mean h[src] + fused GEMM K=256 -> out (x's dtype)

typedef unsigned short u16;

__device__ __forceinline__ float bf2f(u16 v) { return __uint_as_float(((uint32_t)v) << 16); }
__device__ __forceinline__ float bfu_lo(uint32_t u) { return __uint_as_float(u << 16); }
__device__ __forceinline__ float bfu_hi(uint32_t u) { return __uint_as_float(u & 0xffff0000u); }
__device__ __forceinline__ u16 f2bf(float f) {
    uint32_t u = __float_as_uint(f);
    return (u16)((u + 0x7fffu + ((u >> 16) & 1u)) >> 16);
}

// ---------------- probe: dtype flags ----------------
// flags[0..6]: 1 if float array i is bf16, 0 if fp32 (order: x,W1l,W1r,b1,W2l,W2r,b2)
// flags[7]:    1 if edge_index is int64, 0 if int32
__global__ __launch_bounds__(256) void probe_k(
    const void* x, const void* w1l, const void* w1r, const void* b1,
    const void* w2l, const void* w2r, const void* b2, const void* ei,
    int* __restrict__ flags, int ne,
    int c0, int c1, int c2, int c3, int c4, int c5, int c6) {
    __shared__ int cs_s[8];
    int tid = threadIdx.x, a = tid >> 5, lane = tid & 31;
    if (tid < 8) cs_s[tid] = 0;
    __syncthreads();
    if (a < 7) {
        const void* ptrs[7] = {x, w1l, w1r, b1, w2l, w2r, b2};
        int cs[7] = {c0, c1, c2, c3, c4, c5, c6};
        int C = cs[a];
        int stride = C / 32; if (stride < 1) stride = 1;
        long long i = (long long)lane * stride;
        if (i > C - 1) i = C - 1;
        i &= ~1LL;                       // even index: fp32 low-half if fp32
        u16 v = ((const u16*)ptrs[a])[i];
        int e = (v >> 7) & 0xFF;
        int sane = ((e >= 0x50 && e <= 0x97) || v == 0) ? 1 : 0;
        atomicAdd(&cs_s[a], sane);
    } else {
        long long n32 = 2LL * ne;        // int32 words in src region (if int32)
        long long stride = n32 / 32; if (stride < 1) stride = 1;
        long long i = (long long)lane * stride; i |= 1;   // odd word
        if (i >= n32) i = 1;
        int wv = ((const int*)ei)[i];
        atomicAdd(&cs_s[7], wv != 0 ? 1 : 0);
    }
    __syncthreads();
    if (tid < 7) flags[tid] = (cs_s[tid] >= 24) ? 1 : 0;
    if (tid == 7) flags[7] = (cs_s[7] == 0) ? 1 : 0;
}

// ---------------- degree count ----------------
__global__ __launch_bounds__(256) void count_deg(const void* __restrict__ ei,
                                                 int* __restrict__ cnt,
                                                 const int* __restrict__ flags,
                                                 int nn, int ne) {
    int e = blockIdx.x * 256 + threadIdx.x;
    if (e >= ne) return;
    int dst = flags[7] ? (int)((const long long*)ei)[(size_t)ne + e]
                       : ((const int*)ei)[(size_t)ne + e];
    if ((unsigned)dst < (unsigned)nn) atomicAdd(&cnt[dst], 1);
}

// ---------------- scan ----------------
__global__ __launch_bounds__(256) void scan_local(const int* __restrict__ cnt,
                                                  int* __restrict__ off,
                                                  int* __restrict__ partials, int nn) {
    __shared__ int wsum[4];
    int b = blockIdx.x;
    int base = b * 1024 + threadIdx.x * 4;
    int v0 = (base + 0 < nn) ? cnt[base + 0] : 0;
    int v1 = (base + 1 < nn) ? cnt[base + 1] : 0;
    int v2 = (base + 2 < nn) ? cnt[base + 2] : 0;
    int v3 = (base + 3 < nn) ? cnt[base + 3] : 0;
    int s = v0 + v1 + v2 + v3;
    int lane = threadIdx.x & 63;
    int incl = s;
    for (int d = 1; d < 64; d <<= 1) {
        int t = __shfl_up(incl, d, 64);
        if (lane >= d) incl += t;
    }
    int wid = threadIdx.x >> 6;
    if (lane == 63) wsum[wid] = incl;
    __syncthreads();
    int wpre = 0;
    for (int w = 0; w < 4; w++) if (w < wid) wpre += wsum[w];
    int excl = wpre + incl - s;
    if (base + 0 < nn) off[base + 0] = excl;
    if (base + 1 < nn) off[base + 1] = excl + v0;
    if (base + 2 < nn) off[base + 2] = excl + v0 + v1;
    if (base + 3 < nn) off[base + 3] = excl + v0 + v1 + v2;
    if (threadIdx.x == 255) partials[b] = wpre + incl;
}

__global__ __launch_bounds__(1024) void scan_partials(int* __restrict__ partials, int nblk) {
    __shared__ int tmp[1024];
    int tid = threadIdx.x;
    int v = (tid < nblk) ? partials[tid] : 0;
    tmp[tid] = v;
    __syncthreads();
    for (int d = 1; d < 1024; d <<= 1) {
        int t = (tid >= d) ? tmp[tid - d] : 0;
        __syncthreads();
        tmp[tid] += t;
        __syncthreads();
    }
    if (tid < nblk) partials[tid] = tmp[tid] - v;
}

__global__ __launch_bounds__(256) void scan_addback(int* __restrict__ off,
                                                    int* __restrict__ cur,
                                                    const int* __restrict__ partials, int nn) {
    int b = blockIdx.x;
    int p = partials[b];
    int base = b * 1024 + threadIdx.x * 4;
#pragma unroll
    for (int j = 0; j < 4; j++) {
        int i = base + j;
        if (i < nn) { int o = off[i] + p; off[i] = o; cur[i] = o; }
    }
}

// ---------------- CSR fill ----------------
__global__ __launch_bounds__(256) void fill_csr(const void* __restrict__ ei,
                                                int* __restrict__ cur,
                                                int* __restrict__ esrc,
                                                const int* __restrict__ flags,
                                                int nn, int ne) {
    int e = blockIdx.x * 256 + threadIdx.x;
    if (e >= ne) return;
    int src, dst;
    if (flags[7]) {
        const long long* p = (const long long*)ei;
        src = (int)p[e]; dst = (int)p[(size_t)ne + e];
    } else {
        const int* p = (const int*)ei;
        src = p[e]; dst = p[(size_t)ne + e];
    }
    if ((unsigned)dst >= (unsigned)nn || (unsigned)src >= (unsigned)nn) return;
    int pos = atomicAdd(&cur[dst], 1);
    if ((unsigned)pos < (unsigned)ne) esrc[pos] = src;
}

// ---------------- layer 1 ----------------
// 256 thr = 16 nodes x 16 lanes; gather lane owns 4 feats; GEMM 8 acc, K=128.
__global__ __launch_bounds__(256) void layer1(
    const void* __restrict__ x, const int* __restrict__ esrc,
    const int* __restrict__ off, const int* __restrict__ cnt,
    const void* __restrict__ W1l, const void* __restrict__ W1r,
    const void* __restrict__ b1, u16* __restrict__ h,
    const int* __restrict__ flags, int nn) {
    __shared__ u16  w_s[128][128];   // rows 0..63 W1l, 64..127 W1r (bf16)
    __shared__ float in_s[16][128];  // cols 0..63 mean, 64..127 x
    __shared__ float b_s[128];
    int tid = threadIdx.x;
    int node0 = blockIdx.x * 16;
    int xbf = flags[0];

    {   // stage weights -> LDS bf16
        ushort4* dl = (ushort4*)&w_s[0][0];
        ushort4* dr = (ushort4*)(&w_s[0][0] + 8192);
        if (flags[1]) {
            const ushort4* s = (const ushort4*)W1l;
            for (int i = tid; i < 2048; i += 256) dl[i] = s[i];
        } else {
            const float4* s = (const float4*)W1l;
            for (int i = tid; i < 2048; i += 256) {
                float4 f = s[i];
                dl[i] = make_ushort4(f2bf(f.x), f2bf(f.y), f2bf(f.z), f2bf(f.w));
            }
        }
        if (flags[2]) {
            const ushort4* s = (const ushort4*)W1r;
            for (int i = tid; i < 2048; i += 256) dr[i] = s[i];
        } else {
            const float4* s = (const float4*)W1r;
            for (int i = tid; i < 2048; i += 256) {
                float4 f = s[i];
                dr[i] = make_ushort4(f2bf(f.x), f2bf(f.y), f2bf(f.z), f2bf(f.w));
            }
        }
    }
    if (tid < 128) b_s[tid] = flags[3] ? bf2f(((const u16*)b1)[tid]) : ((const float*)b1)[tid];

    int grp = tid >> 4, lane = tid & 15;
    int n = node0 + grp;
    if (n < nn) {
        int beg = off[n];
        int deg = cnt[n];
        float a0 = 0.f, a1 = 0.f, a2 = 0.f, a3 = 0.f;
        if (xbf) {
            const u16* xb = (const u16*)x + lane * 4;
            for (int i = 0; i < deg; i++) {
                int src = esrc[beg + i];
                ushort4 v = *(const ushort4*)(xb + (size_t)src * 64);
                a0 += bf2f(v.x); a1 += bf2f(v.y); a2 += bf2f(v.z); a3 += bf2f(v.w);
            }
        } else {
            const float* xb = (const float*)x + lane * 4;
            for (int i = 0; i < deg; i++) {
                int src = esrc[beg + i];
                float4 v = *(const float4*)(xb + (size_t)src * 64);
                a0 += v.x; a1 += v.y; a2 += v.z; a3 += v.w;
            }
        }
        float inv = 1.0f / (float)(deg > 0 ? deg : 1);
        in_s[grp][lane * 4 + 0] = a0 * inv;
        in_s[grp][lane * 4 + 1] = a1 * inv;
        in_s[grp][lane * 4 + 2] = a2 * inv;
        in_s[grp][lane * 4 + 3] = a3 * inv;
        if (xbf) {
            ushort4 xv = *(const ushort4*)((const u16*)x + (size_t)n * 64 + lane * 4);
            in_s[grp][64 + lane * 4 + 0] = bf2f(xv.x);
            in_s[grp][64 + lane * 4 + 1] = bf2f(xv.y);
            in_s[grp][64 + lane * 4 + 2] = bf2f(xv.z);
            in_s[grp][64 + lane * 4 + 3] = bf2f(xv.w);
        } else {
            float4 xv = *(const float4*)((const float*)x + (size_t)n * 64 + lane * 4);
            in_s[grp][64 + lane * 4 + 0] = xv.x;
            in_s[grp][64 + lane * 4 + 1] = xv.y;
            in_s[grp][64 + lane * 4 + 2] = xv.z;
            in_s[grp][64 + lane * 4 + 3] = xv.w;
        }
    } else {
#pragma unroll
        for (int j = 0; j < 4; j++) {
            in_s[grp][lane * 4 + j] = 0.0f;
            in_s[grp][64 + lane * 4 + j] = 0.0f;
        }
    }
    __syncthreads();

    int jb = (tid & 15) * 8;
    int node = tid >> 4;
    float acc[8];
#pragma unroll
    for (int j = 0; j < 8; j++) acc[j] = 0.0f;
#pragma unroll 4
    for (int k = 0; k < 128; k++) {
        float iv = in_s[node][k];
        uint4 w = *(const uint4*)&w_s[k][jb];
        acc[0] += iv * bfu_lo(w.x);
        acc[1] += iv * bfu_hi(w.x);
        acc[2] += iv * bfu_lo(w.y);
        acc[3] += iv * bfu_hi(w.y);
        acc[4] += iv * bfu_lo(w.z);
        acc[5] += iv * bfu_hi(w.z);
        acc[6] += iv * bfu_lo(w.w);
        acc[7] += iv * bfu_hi(w.w);
    }
    int nw = node0 + node;
    if (nw < nn) {
        u16 ov[8];
#pragma unroll
        for (int j = 0; j < 8; j++) ov[j] = f2bf(fmaxf(acc[j] + b_s[jb + j], 0.0f));
        ushort4* hr = (ushort4*)(h + (size_t)nw * 128 + jb);
        hr[0] = make_ushort4(ov[0], ov[1], ov[2], ov[3]);
        hr[1] = make_ushort4(ov[4], ov[5], ov[6], ov[7]);
    }
}

// ---------------- layer 2 ----------------
// 256 thr = 16 nodes x 16 lanes; gather lane owns 8 feats; GEMM 4 acc, K=256.
__global__ __launch_bounds__(256) void layer2(
    const u16* __restrict__ h, const int* __restrict__ esrc,
    const int* __restrict__ off, const int* __restrict__ cnt,
    const void* __restrict__ W2l, const void* __restrict__ W2r,
    const void* __restrict__ b2, void* __restrict__ out,
    const int* __restrict__ flags, int nn) {
    __shared__ u16  w_s[256][64];
    __shared__ float in_s[16][256];
    __shared__ float b_s[64];
    int tid = threadIdx.x;
    int node0 = blockIdx.x * 16;
    int obf = flags[0];   // output dtype follows x

    {
        ushort4* dl = (ushort4*)&w_s[0][0];
        ushort4* dr = (ushort4*)(&w_s[0][0] + 8192);
        if (flags[4]) {
            const ushort4* s = (const ushort4*)W2l;
            for (int i = tid; i < 2048; i += 256) dl[i] = s[i];
        } else {
            const float4* s = (const float4*)W2l;
            for (int i = tid; i < 2048; i += 256) {
                float4 f = s[i];
                dl[i] = make_ushort4(f2bf(f.x), f2bf(f.y), f2bf(f.z), f2bf(f.w));
            }
        }
        if (flags[5]) {
            const ushort4* s = (const ushort4*)W2r;
            for (int i = tid; i < 2048; i += 256) dr[i] = s[i];
        } else {
            const float4* s = (const float4*)W2r;
            for (int i = tid; i < 2048; i += 256) {
                float4 f = s[i];
                dr[i] = make_ushort4(f2bf(f.x), f2bf(f.y), f2bf(f.z), f2bf(f.w));
            }
        }
    }
    if (tid < 64) b_s[tid] = flags[6] ? bf2f(((const u16*)b2)[tid]) : ((const float*)b2)[tid];

    int grp = tid >> 4, lane = tid & 15;
    int n = node0 + grp;
    if (n < nn) {
        int beg = off[n];
        int deg = cnt[n];
        float a[8];
#pragma unroll
        for (int j = 0; j < 8; j++) a[j] = 0.0f;
        const u16* hb = h + (size_t)lane * 8;
        for (int i = 0; i < deg; i++) {
            int src = esrc[beg + i];
            uint4 v = *(const uint4*)(hb + (size_t)src * 128);
            a[0] += bfu_lo(v.x); a[1] += bfu_hi(v.x);
            a[2] += bfu_lo(v.y); a[3] += bfu_hi(v.y);
            a[4] += bfu_lo(v.z); a[5] += bfu_hi(v.z);
            a[6] += bfu_lo(v.w); a[7] += bfu_hi(v.w);
        }
        float inv = 1.0f / (float)(deg > 0 ? deg : 1);
#pragma unroll
        for (int j = 0; j < 8; j++) in_s[grp][lane * 8 + j] = a[j] * inv;
        uint4 hv = *(const uint4*)(h + (size_t)n * 128 + lane * 8);
        in_s[grp][128 + lane * 8 + 0] = bfu_lo(hv.x);
        in_s[grp][128 + lane * 8 + 1] = bfu_hi(hv.x);
        in_s[grp][128 + lane * 8 + 2] = bfu_lo(hv.y);
        in_s[grp][128 + lane * 8 + 3] = bfu_hi(hv.y);
        in_s[grp][128 + lane * 8 + 4] = bfu_lo(hv.z);
        in_s[grp][128 + lane * 8 + 5] = bfu_hi(hv.z);
        in_s[grp][128 + lane * 8 + 6] = bfu_lo(hv.w);
        in_s[grp][128 + lane * 8 + 7] = bfu_hi(hv.w);
    } else {
#pragma unroll
        for (int j = 0; j < 8; j++) {
            in_s[grp][lane * 8 + j] = 0.0f;
            in_s[grp][128 + lane * 8 + j] = 0.0f;
        }
    }
    __syncthreads();

    int jb = (tid & 15) * 4;
    int node = tid >> 4;
    float acc[4] = {0.0f, 0.0f, 0.0f, 0.0f};
#pragma unroll 4
    for (int k = 0; k < 256; k++) {
        float iv = in_s[node][k];
        uint2 w = *(const uint2*)&w_s[k][jb];
        acc[0] += iv * bfu_lo(w.x);
        acc[1] += iv * bfu_hi(w.x);
        acc[2] += iv * bfu_lo(w.y);
        acc[3] += iv * bfu_hi(w.y);
    }
    int nw = node0 + node;
    if (nw < nn) {
        float r0 = acc[0] + b_s[jb + 0];
        float r1 = acc[1] + b_s[jb + 1];
        float r2 = acc[2] + b_s[jb + 2];
        float r3 = acc[3] + b_s[jb + 3];
        if (obf) {
            *(ushort4*)((u16*)out + (size_t)nw * 64 + jb) =
                make_ushort4(f2bf(r0), f2bf(r1), f2bf(r2), f2bf(r3));
        } else {
            *(float4*)((float*)out + (size_t)nw * 64 + jb) = make_float4(r0, r1, r2, r3);
        }
    }
}

// ---------------- fallback ----------------
__global__ __launch_bounds__(256) void zero_out_k(u16* __restrict__ out, int n) {
    int i = blockIdx.x * 256 + threadIdx.x;
    if (i < n) out[i] = 0;
}

extern "C" void kernel_launch(void* const* d_in, const int* in_sizes, int n_in,
                              void* d_out, int out_size, void* d_ws, size_t ws_size,
                              hipStream_t stream) {
    const void* x   = d_in[0];
    const void* ei  = d_in[1];
    const void* W1l = d_in[2];
    const void* W1r = d_in[3];
    const void* b1  = d_in[4];
    const void* W2l = d_in[5];
    const void* W2r = d_in[6];
    const void* b2  = d_in[7];

    int nn = in_sizes[0] / 64;
    int ne = in_sizes[1] / 2;
    int nblk = (nn + 1023) / 1024;

    auto al = [](size_t v) { return (v + 255) & ~(size_t)255; };
    size_t o_flags = 0;
    size_t o_cnt   = 256;
    size_t o_off   = al(o_cnt + (size_t)nn * 4);
    size_t o_cur   = al(o_off + (size_t)nn * 4);
    size_t o_part  = al(o_cur + (size_t)nn * 4);
    size_t o_esrc  = al(o_part + 4096);
    size_t o_h     = al(o_esrc + (size_t)ne * 4);
    size_t ws_req  = o_h + (size_t)nn * 128 * 2;

    if (ws_size < ws_req || nblk > 1024) {
        zero_out_k<<<(out_size + 255) / 256, 256, 0, stream>>>((u16*)d_out, out_size);
        return;
    }

    char* ws = (char*)d_ws;
    int* flags    = (int*)(ws + o_flags);
    int* cnt      = (int*)(ws + o_cnt);
    int* off      = (int*)(ws + o_off);
    int* cur      = (int*)(ws + o_cur);
    int* partials = (int*)(ws + o_part);
    int* esrc     = (int*)(ws + o_esrc);
    u16* h        = (u16*)(ws + o_h);

    probe_k<<<1, 256, 0, stream>>>(x, W1l, W1r, b1, W2l, W2r, b2, ei, flags, ne,
                                   in_sizes[0], in_sizes[2], in_sizes[3], in_sizes[4],
                                   in_sizes[5], in_sizes[6], in_sizes[7]);
    hipMemsetAsync(cnt, 0, (size_t)nn * 4, stream);
    count_deg<<<(ne + 255) / 256, 256, 0, stream>>>(ei, cnt, flags, nn, ne);
    scan_local<<<nblk, 256, 0, stream>>>(cnt, off, partials, nn);
    scan_partials<<<1, 1024, 0, stream>>>(partials, nblk);
    scan_addback<<<nblk, 256, 0, stream>>>(off, cur, partials, nn);
    fill_csr<<<(ne + 255) / 256, 256, 0, stream>>>(ei, cur, esrc, flags, nn, ne);
    layer1<<<(nn + 15) / 16, 256, 0, stream>>>(x, esrc, off, cnt, W1l, W1r, b1, h, flags, nn);
    layer2<<<(nn + 15) / 16, 256, 0, stream>>>(h, esrc, off, cnt, W2l, W2r, b2, d_out, flags, nn);
}

// Round 4
// 569.738 us; speedup vs baseline: 1.2790x; 1.2790x over previous
//
#include <hip/hip_runtime.h>
#include <hip/hip_bf16.h>
#include <stdint.h>

// GraphSAGE 2-layer encoder — CSR-gather pipeline, runtime dtype detection.
// R4: 32 nodes / 512-thread block, gather unrolled x4 (ILP), bf16 padded in_s
// (bank-conflict-free broadcasts), __launch_bounds__(512,4).

typedef unsigned short u16;

__device__ __forceinline__ float bf2f(u16 v) { return __uint_as_float(((uint32_t)v) << 16); }
__device__ __forceinline__ float bfu_lo(uint32_t u) { return __uint_as_float(u << 16); }
__device__ __forceinline__ float bfu_hi(uint32_t u) { return __uint_as_float(u & 0xffff0000u); }
__device__ __forceinline__ u16 f2bf(float f) {
    uint32_t u = __float_as_uint(f);
    return (u16)((u + 0x7fffu + ((u >> 16) & 1u)) >> 16);
}

// ---------------- probe: dtype flags ----------------
// flags[0..6]: 1 if float array i is bf16, 0 if fp32 (x,W1l,W1r,b1,W2l,W2r,b2)
// flags[7]:    1 if edge_index is int64, 0 if int32
__global__ __launch_bounds__(256) void probe_k(
    const void* x, const void* w1l, const void* w1r, const void* b1,
    const void* w2l, const void* w2r, const void* b2, const void* ei,
    int* __restrict__ flags, int ne,
    int c0, int c1, int c2, int c3, int c4, int c5, int c6) {
    __shared__ int cs_s[8];
    int tid = threadIdx.x, a = tid >> 5, lane = tid & 31;
    if (tid < 8) cs_s[tid] = 0;
    __syncthreads();
    if (a < 7) {
        const void* ptrs[7] = {x, w1l, w1r, b1, w2l, w2r, b2};
        int cs[7] = {c0, c1, c2, c3, c4, c5, c6};
        int C = cs[a];
        int stride = C / 32; if (stride < 1) stride = 1;
        long long i = (long long)lane * stride;
        if (i > C - 1) i = C - 1;
        i &= ~1LL;                       // even index: fp32 low-half if fp32
        u16 v = ((const u16*)ptrs[a])[i];
        int e = (v >> 7) & 0xFF;
        int sane = ((e >= 0x50 && e <= 0x97) || v == 0) ? 1 : 0;
        atomicAdd(&cs_s[a], sane);
    } else {
        long long n32 = 2LL * ne;
        long long stride = n32 / 32; if (stride < 1) stride = 1;
        long long i = (long long)lane * stride; i |= 1;   // odd word
        if (i >= n32) i = 1;
        int wv = ((const int*)ei)[i];
        atomicAdd(&cs_s[7], wv != 0 ? 1 : 0);
    }
    __syncthreads();
    if (tid < 7) flags[tid] = (cs_s[tid] >= 24) ? 1 : 0;
    if (tid == 7) flags[7] = (cs_s[7] == 0) ? 1 : 0;
}

// ---------------- degree count ----------------
__global__ __launch_bounds__(256) void count_deg(const void* __restrict__ ei,
                                                 int* __restrict__ cnt,
                                                 const int* __restrict__ flags,
                                                 int nn, int ne) {
    int e = blockIdx.x * 256 + threadIdx.x;
    if (e >= ne) return;
    int dst = flags[7] ? (int)((const long long*)ei)[(size_t)ne + e]
                       : ((const int*)ei)[(size_t)ne + e];
    if ((unsigned)dst < (unsigned)nn) atomicAdd(&cnt[dst], 1);
}

// ---------------- scan ----------------
__global__ __launch_bounds__(256) void scan_local(const int* __restrict__ cnt,
                                                  int* __restrict__ off,
                                                  int* __restrict__ partials, int nn) {
    __shared__ int wsum[4];
    int b = blockIdx.x;
    int base = b * 1024 + threadIdx.x * 4;
    int v0 = (base + 0 < nn) ? cnt[base + 0] : 0;
    int v1 = (base + 1 < nn) ? cnt[base + 1] : 0;
    int v2 = (base + 2 < nn) ? cnt[base + 2] : 0;
    int v3 = (base + 3 < nn) ? cnt[base + 3] : 0;
    int s = v0 + v1 + v2 + v3;
    int lane = threadIdx.x & 63;
    int incl = s;
    for (int d = 1; d < 64; d <<= 1) {
        int t = __shfl_up(incl, d, 64);
        if (lane >= d) incl += t;
    }
    int wid = threadIdx.x >> 6;
    if (lane == 63) wsum[wid] = incl;
    __syncthreads();
    int wpre = 0;
    for (int w = 0; w < 4; w++) if (w < wid) wpre += wsum[w];
    int excl = wpre + incl - s;
    if (base + 0 < nn) off[base + 0] = excl;
    if (base + 1 < nn) off[base + 1] = excl + v0;
    if (base + 2 < nn) off[base + 2] = excl + v0 + v1;
    if (base + 3 < nn) off[base + 3] = excl + v0 + v1 + v2;
    if (threadIdx.x == 255) partials[b] = wpre + incl;
}

__global__ __launch_bounds__(1024) void scan_partials(int* __restrict__ partials, int nblk) {
    __shared__ int tmp[1024];
    int tid = threadIdx.x;
    int v = (tid < nblk) ? partials[tid] : 0;
    tmp[tid] = v;
    __syncthreads();
    for (int d = 1; d < 1024; d <<= 1) {
        int t = (tid >= d) ? tmp[tid - d] : 0;
        __syncthreads();
        tmp[tid] += t;
        __syncthreads();
    }
    if (tid < nblk) partials[tid] = tmp[tid] - v;
}

__global__ __launch_bounds__(256) void scan_addback(int* __restrict__ off,
                                                    int* __restrict__ cur,
                                                    const int* __restrict__ partials, int nn) {
    int b = blockIdx.x;
    int p = partials[b];
    int base = b * 1024 + threadIdx.x * 4;
#pragma unroll
    for (int j = 0; j < 4; j++) {
        int i = base + j;
        if (i < nn) { int o = off[i] + p; off[i] = o; cur[i] = o; }
    }
}

// ---------------- CSR fill ----------------
__global__ __launch_bounds__(256) void fill_csr(const void* __restrict__ ei,
                                                int* __restrict__ cur,
                                                int* __restrict__ esrc,
                                                const int* __restrict__ flags,
                                                int nn, int ne) {
    int e = blockIdx.x * 256 + threadIdx.x;
    if (e >= ne) return;
    int src, dst;
    if (flags[7]) {
        const long long* p = (const long long*)ei;
        src = (int)p[e]; dst = (int)p[(size_t)ne + e];
    } else {
        const int* p = (const int*)ei;
        src = p[e]; dst = p[(size_t)ne + e];
    }
    if ((unsigned)dst >= (unsigned)nn || (unsigned)src >= (unsigned)nn) return;
    int pos = atomicAdd(&cur[dst], 1);
    if ((unsigned)pos < (unsigned)ne) esrc[pos] = src;
}

// ---------------- layer 1 ----------------
// 512 thr = 32 nodes x 16 lanes; gather lane owns 4 feats, unrolled x4.
// GEMM: thread (node=tid>>4, jb=(tid&15)*8), 8 acc, K=128 (bf16 LDS inputs).
__global__ __launch_bounds__(512, 4) void layer1(
    const void* __restrict__ x, const int* __restrict__ esrc,
    const int* __restrict__ off, const int* __restrict__ cnt,
    const void* __restrict__ W1l, const void* __restrict__ W1r,
    const void* __restrict__ b1, u16* __restrict__ h,
    const int* __restrict__ flags, int nn) {
    __shared__ u16 w_s[128][128];    // 32 KB: rows 0..63 W1l, 64..127 W1r
    __shared__ u16 in_s[32][136];    // 8.5 KB: 0..63 mean, 64..127 x, pad 8
    __shared__ float b_s[128];
    int tid = threadIdx.x;
    int node0 = blockIdx.x * 32;
    int xbf = flags[0];

    {
        ushort4* dl = (ushort4*)&w_s[0][0];
        ushort4* dr = dl + 2048;
        if (flags[1]) {
            const ushort4* s = (const ushort4*)W1l;
            for (int i = tid; i < 2048; i += 512) dl[i] = s[i];
        } else {
            const float4* s = (const float4*)W1l;
            for (int i = tid; i < 2048; i += 512) {
                float4 f = s[i];
                dl[i] = make_ushort4(f2bf(f.x), f2bf(f.y), f2bf(f.z), f2bf(f.w));
            }
        }
        if (flags[2]) {
            const ushort4* s = (const ushort4*)W1r;
            for (int i = tid; i < 2048; i += 512) dr[i] = s[i];
        } else {
            const float4* s = (const float4*)W1r;
            for (int i = tid; i < 2048; i += 512) {
                float4 f = s[i];
                dr[i] = make_ushort4(f2bf(f.x), f2bf(f.y), f2bf(f.z), f2bf(f.w));
            }
        }
    }
    if (tid < 128) b_s[tid] = flags[3] ? bf2f(((const u16*)b1)[tid]) : ((const float*)b1)[tid];

    int grp = tid >> 4, lane = tid & 15;
    int n = node0 + grp;
    if (n < nn) {
        int beg = off[n], deg = cnt[n];
        float a0 = 0.f, a1 = 0.f, a2 = 0.f, a3 = 0.f;
        int i = 0;
        if (xbf) {
            const u16* xb = (const u16*)x + lane * 4;
            for (; i + 4 <= deg; i += 4) {
                int s0 = esrc[beg + i + 0], s1 = esrc[beg + i + 1];
                int s2 = esrc[beg + i + 2], s3 = esrc[beg + i + 3];
                ushort4 v0 = *(const ushort4*)(xb + (size_t)s0 * 64);
                ushort4 v1 = *(const ushort4*)(xb + (size_t)s1 * 64);
                ushort4 v2 = *(const ushort4*)(xb + (size_t)s2 * 64);
                ushort4 v3 = *(const ushort4*)(xb + (size_t)s3 * 64);
                a0 += (bf2f(v0.x) + bf2f(v1.x)) + (bf2f(v2.x) + bf2f(v3.x));
                a1 += (bf2f(v0.y) + bf2f(v1.y)) + (bf2f(v2.y) + bf2f(v3.y));
                a2 += (bf2f(v0.z) + bf2f(v1.z)) + (bf2f(v2.z) + bf2f(v3.z));
                a3 += (bf2f(v0.w) + bf2f(v1.w)) + (bf2f(v2.w) + bf2f(v3.w));
            }
            for (; i < deg; i++) {
                int s0 = esrc[beg + i];
                ushort4 v = *(const ushort4*)(xb + (size_t)s0 * 64);
                a0 += bf2f(v.x); a1 += bf2f(v.y); a2 += bf2f(v.z); a3 += bf2f(v.w);
            }
        } else {
            const float* xb = (const float*)x + lane * 4;
            for (; i + 4 <= deg; i += 4) {
                int s0 = esrc[beg + i + 0], s1 = esrc[beg + i + 1];
                int s2 = esrc[beg + i + 2], s3 = esrc[beg + i + 3];
                float4 v0 = *(const float4*)(xb + (size_t)s0 * 64);
                float4 v1 = *(const float4*)(xb + (size_t)s1 * 64);
                float4 v2 = *(const float4*)(xb + (size_t)s2 * 64);
                float4 v3 = *(const float4*)(xb + (size_t)s3 * 64);
                a0 += (v0.x + v1.x) + (v2.x + v3.x);
                a1 += (v0.y + v1.y) + (v2.y + v3.y);
                a2 += (v0.z + v1.z) + (v2.z + v3.z);
                a3 += (v0.w + v1.w) + (v2.w + v3.w);
            }
            for (; i < deg; i++) {
                int s0 = esrc[beg + i];
                float4 v = *(const float4*)(xb + (size_t)s0 * 64);
                a0 += v.x; a1 += v.y; a2 += v.z; a3 += v.w;
            }
        }
        float inv = 1.0f / (float)(deg > 0 ? deg : 1);
        *(ushort4*)&in_s[grp][lane * 4] =
            make_ushort4(f2bf(a0 * inv), f2bf(a1 * inv), f2bf(a2 * inv), f2bf(a3 * inv));
        if (xbf) {
            *(ushort4*)&in_s[grp][64 + lane * 4] =
                *(const ushort4*)((const u16*)x + (size_t)n * 64 + lane * 4);
        } else {
            float4 xv = *(const float4*)((const float*)x + (size_t)n * 64 + lane * 4);
            *(ushort4*)&in_s[grp][64 + lane * 4] =
                make_ushort4(f2bf(xv.x), f2bf(xv.y), f2bf(xv.z), f2bf(xv.w));
        }
    } else {
        *(ushort4*)&in_s[grp][lane * 4] = make_ushort4(0, 0, 0, 0);
        *(ushort4*)&in_s[grp][64 + lane * 4] = make_ushort4(0, 0, 0, 0);
    }
    __syncthreads();

    int jb = lane * 8;
    float acc[8];
#pragma unroll
    for (int j = 0; j < 8; j++) acc[j] = 0.0f;
#pragma unroll 4
    for (int kk = 0; kk < 64; kk++) {
        uint32_t iv2 = *(const uint32_t*)&in_s[grp][kk * 2];
        float iv0 = bfu_lo(iv2), iv1 = bfu_hi(iv2);
        uint4 w0 = *(const uint4*)&w_s[kk * 2][jb];
        uint4 w1 = *(const uint4*)&w_s[kk * 2 + 1][jb];
        acc[0] += iv0 * bfu_lo(w0.x); acc[1] += iv0 * bfu_hi(w0.x);
        acc[2] += iv0 * bfu_lo(w0.y); acc[3] += iv0 * bfu_hi(w0.y);
        acc[4] += iv0 * bfu_lo(w0.z); acc[5] += iv0 * bfu_hi(w0.z);
        acc[6] += iv0 * bfu_lo(w0.w); acc[7] += iv0 * bfu_hi(w0.w);
        acc[0] += iv1 * bfu_lo(w1.x); acc[1] += iv1 * bfu_hi(w1.x);
        acc[2] += iv1 * bfu_lo(w1.y); acc[3] += iv1 * bfu_hi(w1.y);
        acc[4] += iv1 * bfu_lo(w1.z); acc[5] += iv1 * bfu_hi(w1.z);
        acc[6] += iv1 * bfu_lo(w1.w); acc[7] += iv1 * bfu_hi(w1.w);
    }
    if (n < nn) {
        u16 ov[8];
#pragma unroll
        for (int j = 0; j < 8; j++) ov[j] = f2bf(fmaxf(acc[j] + b_s[jb + j], 0.0f));
        ushort4* hr = (ushort4*)(h + (size_t)n * 128 + jb);
        hr[0] = make_ushort4(ov[0], ov[1], ov[2], ov[3]);
        hr[1] = make_ushort4(ov[4], ov[5], ov[6], ov[7]);
    }
}

// ---------------- layer 2 ----------------
// 512 thr = 32 nodes x 16 lanes; gather lane owns 8 feats (uint4), unrolled x4.
// GEMM: thread (node=tid>>4, jb=(tid&15)*4), 4 acc, K=256 (bf16 LDS inputs).
__global__ __launch_bounds__(512, 4) void layer2(
    const u16* __restrict__ h, const int* __restrict__ esrc,
    const int* __restrict__ off, const int* __restrict__ cnt,
    const void* __restrict__ W2l, const void* __restrict__ W2r,
    const void* __restrict__ b2, void* __restrict__ out,
    const int* __restrict__ flags, int nn) {
    __shared__ u16 w_s[256][64];     // 32 KB: rows 0..127 W2l, 128..255 W2r
    __shared__ u16 in_s[32][264];    // 16.5 KB: 0..127 mean, 128..255 h, pad 8
    __shared__ float b_s[64];
    int tid = threadIdx.x;
    int node0 = blockIdx.x * 32;
    int obf = flags[0];

    {
        ushort4* dl = (ushort4*)&w_s[0][0];
        ushort4* dr = dl + 2048;
        if (flags[4]) {
            const ushort4* s = (const ushort4*)W2l;
            for (int i = tid; i < 2048; i += 512) dl[i] = s[i];
        } else {
            const float4* s = (const float4*)W2l;
            for (int i = tid; i < 2048; i += 512) {
                float4 f = s[i];
                dl[i] = make_ushort4(f2bf(f.x), f2bf(f.y), f2bf(f.z), f2bf(f.w));
            }
        }
        if (flags[5]) {
            const ushort4* s = (const ushort4*)W2r;
            for (int i = tid; i < 2048; i += 512) dr[i] = s[i];
        } else {
            const float4* s = (const float4*)W2r;
            for (int i = tid; i < 2048; i += 512) {
                float4 f = s[i];
                dr[i] = make_ushort4(f2bf(f.x), f2bf(f.y), f2bf(f.z), f2bf(f.w));
            }
        }
    }
    if (tid < 64) b_s[tid] = flags[6] ? bf2f(((const u16*)b2)[tid]) : ((const float*)b2)[tid];

    int grp = tid >> 4, lane = tid & 15;
    int n = node0 + grp;
    if (n < nn) {
        int beg = off[n], deg = cnt[n];
        float a[8];
#pragma unroll
        for (int j = 0; j < 8; j++) a[j] = 0.0f;
        const u16* hb = h + (size_t)lane * 8;
        int i = 0;
        for (; i + 4 <= deg; i += 4) {
            int s0 = esrc[beg + i + 0], s1 = esrc[beg + i + 1];
            int s2 = esrc[beg + i + 2], s3 = esrc[beg + i + 3];
            uint4 v0 = *(const uint4*)(hb + (size_t)s0 * 128);
            uint4 v1 = *(const uint4*)(hb + (size_t)s1 * 128);
            uint4 v2 = *(const uint4*)(hb + (size_t)s2 * 128);
            uint4 v3 = *(const uint4*)(hb + (size_t)s3 * 128);
            a[0] += (bfu_lo(v0.x) + bfu_lo(v1.x)) + (bfu_lo(v2.x) + bfu_lo(v3.x));
            a[1] += (bfu_hi(v0.x) + bfu_hi(v1.x)) + (bfu_hi(v2.x) + bfu_hi(v3.x));
            a[2] += (bfu_lo(v0.y) + bfu_lo(v1.y)) + (bfu_lo(v2.y) + bfu_lo(v3.y));
            a[3] += (bfu_hi(v0.y) + bfu_hi(v1.y)) + (bfu_hi(v2.y) + bfu_hi(v3.y));
            a[4] += (bfu_lo(v0.z) + bfu_lo(v1.z)) + (bfu_lo(v2.z) + bfu_lo(v3.z));
            a[5] += (bfu_hi(v0.z) + bfu_hi(v1.z)) + (bfu_hi(v2.z) + bfu_hi(v3.z));
            a[6] += (bfu_lo(v0.w) + bfu_lo(v1.w)) + (bfu_lo(v2.w) + bfu_lo(v3.w));
            a[7] += (bfu_hi(v0.w) + bfu_hi(v1.w)) + (bfu_hi(v2.w) + bfu_hi(v3.w));
        }
        for (; i < deg; i++) {
            int s0 = esrc[beg + i];
            uint4 v = *(const uint4*)(hb + (size_t)s0 * 128);
            a[0] += bfu_lo(v.x); a[1] += bfu_hi(v.x);
            a[2] += bfu_lo(v.y); a[3] += bfu_hi(v.y);
            a[4] += bfu_lo(v.z); a[5] += bfu_hi(v.z);
            a[6] += bfu_lo(v.w); a[7] += bfu_hi(v.w);
        }
        float inv = 1.0f / (float)(deg > 0 ? deg : 1);
        *(ushort4*)&in_s[grp][lane * 8] =
            make_ushort4(f2bf(a[0] * inv), f2bf(a[1] * inv), f2bf(a[2] * inv), f2bf(a[3] * inv));
        *(ushort4*)&in_s[grp][lane * 8 + 4] =
            make_ushort4(f2bf(a[4] * inv), f2bf(a[5] * inv), f2bf(a[6] * inv), f2bf(a[7] * inv));
        // own h row is already bf16 — copy raw
        uint4 hv = *(const uint4*)(h + (size_t)n * 128 + lane * 8);
        *(uint4*)&in_s[grp][128 + lane * 8] = hv;
    } else {
        *(ushort4*)&in_s[grp][lane * 8] = make_ushort4(0, 0, 0, 0);
        *(ushort4*)&in_s[grp][lane * 8 + 4] = make_ushort4(0, 0, 0, 0);
        *(uint4*)&in_s[grp][128 + lane * 8] = make_uint4(0, 0, 0, 0);
    }
    __syncthreads();

    int jb = lane * 4;
    float acc[4] = {0.0f, 0.0f, 0.0f, 0.0f};
#pragma unroll 4
    for (int kk = 0; kk < 128; kk++) {
        uint32_t iv2 = *(const uint32_t*)&in_s[grp][kk * 2];
        float iv0 = bfu_lo(iv2), iv1 = bfu_hi(iv2);
        uint2 w0 = *(const uint2*)&w_s[kk * 2][jb];
        uint2 w1 = *(const uint2*)&w_s[kk * 2 + 1][jb];
        acc[0] += iv0 * bfu_lo(w0.x); acc[1] += iv0 * bfu_hi(w0.x);
        acc[2] += iv0 * bfu_lo(w0.y); acc[3] += iv0 * bfu_hi(w0.y);
        acc[0] += iv1 * bfu_lo(w1.x); acc[1] += iv1 * bfu_hi(w1.x);
        acc[2] += iv1 * bfu_lo(w1.y); acc[3] += iv1 * bfu_hi(w1.y);
    }
    if (n < nn) {
        float r0 = acc[0] + b_s[jb + 0];
        float r1 = acc[1] + b_s[jb + 1];
        float r2 = acc[2] + b_s[jb + 2];
        float r3 = acc[3] + b_s[jb + 3];
        if (obf) {
            *(ushort4*)((u16*)out + (size_t)n * 64 + jb) =
                make_ushort4(f2bf(r0), f2bf(r1), f2bf(r2), f2bf(r3));
        } else {
            *(float4*)((float*)out + (size_t)n * 64 + jb) = make_float4(r0, r1, r2, r3);
        }
    }
}

// ---------------- fallback ----------------
__global__ __launch_bounds__(256) void zero_out_k(u16* __restrict__ out, int n) {
    int i = blockIdx.x * 256 + threadIdx.x;
    if (i < n) out[i] = 0;
}

extern "C" void kernel_launch(void* const* d_in, const int* in_sizes, int n_in,
                              void* d_out, int out_size, void* d_ws, size_t ws_size,
                              hipStream_t stream) {
    const void* x   = d_in[0];
    const void* ei  = d_in[1];
    const void* W1l = d_in[2];
    const void* W1r = d_in[3];
    const void* b1  = d_in[4];
    const void* W2l = d_in[5];
    const void* W2r = d_in[6];
    const void* b2  = d_in[7];

    int nn = in_sizes[0] / 64;
    int ne = in_sizes[1] / 2;
    int nblk = (nn + 1023) / 1024;

    auto al = [](size_t v) { return (v + 255) & ~(size_t)255; };
    size_t o_flags = 0;
    size_t o_cnt   = 256;
    size_t o_off   = al(o_cnt + (size_t)nn * 4);
    size_t o_cur   = al(o_off + (size_t)nn * 4);
    size_t o_part  = al(o_cur + (size_t)nn * 4);
    size_t o_esrc  = al(o_part + 4096);
    size_t o_h     = al(o_esrc + (size_t)ne * 4);
    size_t ws_req  = o_h + (size_t)nn * 128 * 2;

    if (ws_size < ws_req || nblk > 1024) {
        zero_out_k<<<(out_size + 255) / 256, 256, 0, stream>>>((u16*)d_out, out_size);
        return;
    }

    char* ws = (char*)d_ws;
    int* flags    = (int*)(ws + o_flags);
    int* cnt      = (int*)(ws + o_cnt);
    int* off      = (int*)(ws + o_off);
    int* cur      = (int*)(ws + o_cur);
    int* partials = (int*)(ws + o_part);
    int* esrc     = (int*)(ws + o_esrc);
    u16* h        = (u16*)(ws + o_h);

    probe_k<<<1, 256, 0, stream>>>(x, W1l, W1r, b1, W2l, W2r, b2, ei, flags, ne,
                                   in_sizes[0], in_sizes[2], in_sizes[3], in_sizes[4],
                                   in_sizes[5], in_sizes[6], in_sizes[7]);
    hipMemsetAsync(cnt, 0, (size_t)nn * 4, stream);
    count_deg<<<(ne + 255) / 256, 256, 0, stream>>>(ei, cnt, flags, nn, ne);
    scan_local<<<nblk, 256, 0, stream>>>(cnt, off, partials, nn);
    scan_partials<<<1, 1024, 0, stream>>>(partials, nblk);
    scan_addback<<<nblk, 256, 0, stream>>>(off, cur, partials, nn);
    fill_csr<<<(ne + 255) / 256, 256, 0, stream>>>(ei, cur, esrc, flags, nn, ne);
    int lb = (nn + 31) / 32;
    layer1<<<lb, 512, 0, stream>>>(x, esrc, off, cnt, W1l, W1r, b1, h, flags, nn);
    layer2<<<lb, 512, 0, stream>>>(h, esrc, off, cnt, W2l, W2r, b2, d_out, flags, nn);
}

// Round 5
// 445.195 us; speedup vs baseline: 1.6368x; 1.2797x over previous
//
#include <hip/hip_runtime.h>
#include <hip/hip_bf16.h>
#include <stdint.h>

// GraphSAGE 2-layer encoder — CSR-gather + MFMA GEMM, runtime dtype detection.
// R5: GEMM phases use v_mfma_f32_16x16x32_bf16 (weights transposed in LDS,
// [n][k] + pad so B-frags are contiguous b128); gather unrolled x8.

typedef unsigned short u16;
typedef __attribute__((ext_vector_type(8))) short short8;   // bf16x8 A/B frag
typedef __attribute__((ext_vector_type(4))) float f32x4;    // fp32x4 C/D frag

__device__ __forceinline__ float bf2f(u16 v) { return __uint_as_float(((uint32_t)v) << 16); }
__device__ __forceinline__ float bfu_lo(uint32_t u) { return __uint_as_float(u << 16); }
__device__ __forceinline__ float bfu_hi(uint32_t u) { return __uint_as_float(u & 0xffff0000u); }
__device__ __forceinline__ u16 f2bf(float f) {
    uint32_t u = __float_as_uint(f);
    return (u16)((u + 0x7fffu + ((u >> 16) & 1u)) >> 16);
}

// ---------------- probe: dtype flags ----------------
// flags[0..6]: 1 if float array i is bf16, 0 if fp32 (x,W1l,W1r,b1,W2l,W2r,b2)
// flags[7]:    1 if edge_index is int64, 0 if int32
__global__ __launch_bounds__(256) void probe_k(
    const void* x, const void* w1l, const void* w1r, const void* b1,
    const void* w2l, const void* w2r, const void* b2, const void* ei,
    int* __restrict__ flags, int ne,
    int c0, int c1, int c2, int c3, int c4, int c5, int c6) {
    __shared__ int cs_s[8];
    int tid = threadIdx.x, a = tid >> 5, lane = tid & 31;
    if (tid < 8) cs_s[tid] = 0;
    __syncthreads();
    if (a < 7) {
        const void* ptrs[7] = {x, w1l, w1r, b1, w2l, w2r, b2};
        int cs[7] = {c0, c1, c2, c3, c4, c5, c6};
        int C = cs[a];
        int stride = C / 32; if (stride < 1) stride = 1;
        long long i = (long long)lane * stride;
        if (i > C - 1) i = C - 1;
        i &= ~1LL;                       // even index: fp32 low-half if fp32
        u16 v = ((const u16*)ptrs[a])[i];
        int e = (v >> 7) & 0xFF;
        int sane = ((e >= 0x50 && e <= 0x97) || v == 0) ? 1 : 0;
        atomicAdd(&cs_s[a], sane);
    } else {
        long long n32 = 2LL * ne;
        long long stride = n32 / 32; if (stride < 1) stride = 1;
        long long i = (long long)lane * stride; i |= 1;   // odd word
        if (i >= n32) i = 1;
        int wv = ((const int*)ei)[i];
        atomicAdd(&cs_s[7], wv != 0 ? 1 : 0);
    }
    __syncthreads();
    if (tid < 7) flags[tid] = (cs_s[tid] >= 24) ? 1 : 0;
    if (tid == 7) flags[7] = (cs_s[7] == 0) ? 1 : 0;
}

// ---------------- degree count ----------------
__global__ __launch_bounds__(256) void count_deg(const void* __restrict__ ei,
                                                 int* __restrict__ cnt,
                                                 const int* __restrict__ flags,
                                                 int nn, int ne) {
    int e = blockIdx.x * 256 + threadIdx.x;
    if (e >= ne) return;
    int dst = flags[7] ? (int)((const long long*)ei)[(size_t)ne + e]
                       : ((const int*)ei)[(size_t)ne + e];
    if ((unsigned)dst < (unsigned)nn) atomicAdd(&cnt[dst], 1);
}

// ---------------- scan ----------------
__global__ __launch_bounds__(256) void scan_local(const int* __restrict__ cnt,
                                                  int* __restrict__ off,
                                                  int* __restrict__ partials, int nn) {
    __shared__ int wsum[4];
    int b = blockIdx.x;
    int base = b * 1024 + threadIdx.x * 4;
    int v0 = (base + 0 < nn) ? cnt[base + 0] : 0;
    int v1 = (base + 1 < nn) ? cnt[base + 1] : 0;
    int v2 = (base + 2 < nn) ? cnt[base + 2] : 0;
    int v3 = (base + 3 < nn) ? cnt[base + 3] : 0;
    int s = v0 + v1 + v2 + v3;
    int lane = threadIdx.x & 63;
    int incl = s;
    for (int d = 1; d < 64; d <<= 1) {
        int t = __shfl_up(incl, d, 64);
        if (lane >= d) incl += t;
    }
    int wid = threadIdx.x >> 6;
    if (lane == 63) wsum[wid] = incl;
    __syncthreads();
    int wpre = 0;
    for (int w = 0; w < 4; w++) if (w < wid) wpre += wsum[w];
    int excl = wpre + incl - s;
    if (base + 0 < nn) off[base + 0] = excl;
    if (base + 1 < nn) off[base + 1] = excl + v0;
    if (base + 2 < nn) off[base + 2] = excl + v0 + v1;
    if (base + 3 < nn) off[base + 3] = excl + v0 + v1 + v2;
    if (threadIdx.x == 255) partials[b] = wpre + incl;
}

__global__ __launch_bounds__(1024) void scan_partials(int* __restrict__ partials, int nblk) {
    __shared__ int tmp[1024];
    int tid = threadIdx.x;
    int v = (tid < nblk) ? partials[tid] : 0;
    tmp[tid] = v;
    __syncthreads();
    for (int d = 1; d < 1024; d <<= 1) {
        int t = (tid >= d) ? tmp[tid - d] : 0;
        __syncthreads();
        tmp[tid] += t;
        __syncthreads();
    }
    if (tid < nblk) partials[tid] = tmp[tid] - v;
}

__global__ __launch_bounds__(256) void scan_addback(int* __restrict__ off,
                                                    int* __restrict__ cur,
                                                    const int* __restrict__ partials, int nn) {
    int b = blockIdx.x;
    int p = partials[b];
    int base = b * 1024 + threadIdx.x * 4;
#pragma unroll
    for (int j = 0; j < 4; j++) {
        int i = base + j;
        if (i < nn) { int o = off[i] + p; off[i] = o; cur[i] = o; }
    }
}

// ---------------- CSR fill ----------------
__global__ __launch_bounds__(256) void fill_csr(const void* __restrict__ ei,
                                                int* __restrict__ cur,
                                                int* __restrict__ esrc,
                                                const int* __restrict__ flags,
                                                int nn, int ne) {
    int e = blockIdx.x * 256 + threadIdx.x;
    if (e >= ne) return;
    int src, dst;
    if (flags[7]) {
        const long long* p = (const long long*)ei;
        src = (int)p[e]; dst = (int)p[(size_t)ne + e];
    } else {
        const int* p = (const int*)ei;
        src = p[e]; dst = p[(size_t)ne + e];
    }
    if ((unsigned)dst >= (unsigned)nn || (unsigned)src >= (unsigned)nn) return;
    int pos = atomicAdd(&cur[dst], 1);
    if ((unsigned)pos < (unsigned)ne) esrc[pos] = src;
}

// ---------------- layer 1 ----------------
// 512 thr = 32 nodes x 16 lanes (gather) = 8 waves (MFMA).
// Tile: M=32, N=128, K=128. Wave w: n0=w*16, both m-tiles (0,16). 4 K-chunks.
__global__ __launch_bounds__(512, 4) void layer1(
    const void* __restrict__ x, const int* __restrict__ esrc,
    const int* __restrict__ off, const int* __restrict__ cnt,
    const void* __restrict__ W1l, const void* __restrict__ W1r,
    const void* __restrict__ b1, u16* __restrict__ h,
    const int* __restrict__ flags, int nn) {
    __shared__ u16 wt_s[128][136];   // [n][k] transposed; k 0..63 W1l, 64..127 W1r
    __shared__ u16 in_s[32][136];    // [m][k]; k 0..63 mean, 64..127 x
    __shared__ float b_s[128];
    int tid = threadIdx.x;
    int node0 = blockIdx.x * 32;
    int xbf = flags[0];

    // ---- stage weights transposed into LDS (bf16) ----
    // W1l global: [64 k][128 n] row-major; ushort4 i -> k=i>>5, n=(i&31)*4.
    if (flags[1]) {
        const ushort4* s = (const ushort4*)W1l;
        for (int i = tid; i < 2048; i += 512) {
            ushort4 v = s[i]; int k = i >> 5, n = (i & 31) * 4;
            wt_s[n + 0][k] = v.x; wt_s[n + 1][k] = v.y;
            wt_s[n + 2][k] = v.z; wt_s[n + 3][k] = v.w;
        }
    } else {
        const float4* s = (const float4*)W1l;
        for (int i = tid; i < 2048; i += 512) {
            float4 f = s[i]; int k = i >> 5, n = (i & 31) * 4;
            wt_s[n + 0][k] = f2bf(f.x); wt_s[n + 1][k] = f2bf(f.y);
            wt_s[n + 2][k] = f2bf(f.z); wt_s[n + 3][k] = f2bf(f.w);
        }
    }
    if (flags[2]) {
        const ushort4* s = (const ushort4*)W1r;
        for (int i = tid; i < 2048; i += 512) {
            ushort4 v = s[i]; int k = 64 + (i >> 5), n = (i & 31) * 4;
            wt_s[n + 0][k] = v.x; wt_s[n + 1][k] = v.y;
            wt_s[n + 2][k] = v.z; wt_s[n + 3][k] = v.w;
        }
    } else {
        const float4* s = (const float4*)W1r;
        for (int i = tid; i < 2048; i += 512) {
            float4 f = s[i]; int k = 64 + (i >> 5), n = (i & 31) * 4;
            wt_s[n + 0][k] = f2bf(f.x); wt_s[n + 1][k] = f2bf(f.y);
            wt_s[n + 2][k] = f2bf(f.z); wt_s[n + 3][k] = f2bf(f.w);
        }
    }
    if (tid < 128) b_s[tid] = flags[3] ? bf2f(((const u16*)b1)[tid]) : ((const float*)b1)[tid];

    // ---- gather-mean phase (16 lanes/node, 4 feats/lane, unroll x8) ----
    int grp = tid >> 4, gl = tid & 15;
    int n = node0 + grp;
    if (n < nn) {
        int beg = off[n], deg = cnt[n];
        float a0 = 0.f, a1 = 0.f, a2 = 0.f, a3 = 0.f;
        int i = 0;
        if (xbf) {
            const u16* xb = (const u16*)x + gl * 4;
            for (; i + 8 <= deg; i += 8) {
                ushort4 v[8];
#pragma unroll
                for (int j = 0; j < 8; j++) {
                    int s0 = esrc[beg + i + j];
                    v[j] = *(const ushort4*)(xb + (size_t)s0 * 64);
                }
#pragma unroll
                for (int j = 0; j < 8; j++) {
                    a0 += bf2f(v[j].x); a1 += bf2f(v[j].y);
                    a2 += bf2f(v[j].z); a3 += bf2f(v[j].w);
                }
            }
            for (; i < deg; i++) {
                int s0 = esrc[beg + i];
                ushort4 v = *(const ushort4*)(xb + (size_t)s0 * 64);
                a0 += bf2f(v.x); a1 += bf2f(v.y); a2 += bf2f(v.z); a3 += bf2f(v.w);
            }
        } else {
            const float* xb = (const float*)x + gl * 4;
            for (; i + 8 <= deg; i += 8) {
                float4 v[8];
#pragma unroll
                for (int j = 0; j < 8; j++) {
                    int s0 = esrc[beg + i + j];
                    v[j] = *(const float4*)(xb + (size_t)s0 * 64);
                }
#pragma unroll
                for (int j = 0; j < 8; j++) {
                    a0 += v[j].x; a1 += v[j].y; a2 += v[j].z; a3 += v[j].w;
                }
            }
            for (; i < deg; i++) {
                int s0 = esrc[beg + i];
                float4 v = *(const float4*)(xb + (size_t)s0 * 64);
                a0 += v.x; a1 += v.y; a2 += v.z; a3 += v.w;
            }
        }
        float inv = 1.0f / (float)(deg > 0 ? deg : 1);
        *(ushort4*)&in_s[grp][gl * 4] =
            make_ushort4(f2bf(a0 * inv), f2bf(a1 * inv), f2bf(a2 * inv), f2bf(a3 * inv));
        if (xbf) {
            *(ushort4*)&in_s[grp][64 + gl * 4] =
                *(const ushort4*)((const u16*)x + (size_t)n * 64 + gl * 4);
        } else {
            float4 xv = *(const float4*)((const float*)x + (size_t)n * 64 + gl * 4);
            *(ushort4*)&in_s[grp][64 + gl * 4] =
                make_ushort4(f2bf(xv.x), f2bf(xv.y), f2bf(xv.z), f2bf(xv.w));
        }
    } else {
        *(ushort4*)&in_s[grp][gl * 4] = make_ushort4(0, 0, 0, 0);
        *(ushort4*)&in_s[grp][64 + gl * 4] = make_ushort4(0, 0, 0, 0);
    }
    __syncthreads();

    // ---- MFMA phase ----
    int wv = tid >> 6, lane = tid & 63;
    int l15 = lane & 15, q = lane >> 4;
    int n0 = wv * 16;
    f32x4 acc0 = {0.f, 0.f, 0.f, 0.f};
    f32x4 acc1 = {0.f, 0.f, 0.f, 0.f};
    const u16* arow0 = &in_s[l15][q * 8];
    const u16* arow1 = &in_s[16 + l15][q * 8];
    const u16* brow  = &wt_s[n0 + l15][q * 8];
#pragma unroll
    for (int kc = 0; kc < 4; kc++) {
        short8 a0 = *(const short8*)(arow0 + kc * 32);
        short8 a1 = *(const short8*)(arow1 + kc * 32);
        short8 b  = *(const short8*)(brow  + kc * 32);
        acc0 = __builtin_amdgcn_mfma_f32_16x16x32_bf16(a0, b, acc0, 0, 0, 0);
        acc1 = __builtin_amdgcn_mfma_f32_16x16x32_bf16(a1, b, acc1, 0, 0, 0);
    }
    int nc = n0 + l15;
    float bias = b_s[nc];
#pragma unroll
    for (int r = 0; r < 4; r++) {
        int m = q * 4 + r;
        int nd = node0 + m;
        if (nd < nn) h[(size_t)nd * 128 + nc] = f2bf(fmaxf(acc0[r] + bias, 0.0f));
        nd = node0 + 16 + m;
        if (nd < nn) h[(size_t)nd * 128 + nc] = f2bf(fmaxf(acc1[r] + bias, 0.0f));
    }
}

// ---------------- layer 2 ----------------
// 512 thr = 32 nodes x 16 lanes (gather) = 8 waves (MFMA).
// Tile: M=32, N=64, K=256. Wave w: m0=(w>>2)*16, n0=(w&3)*16. 8 K-chunks.
__global__ __launch_bounds__(512, 4) void layer2(
    const u16* __restrict__ h, const int* __restrict__ esrc,
    const int* __restrict__ off, const int* __restrict__ cnt,
    const void* __restrict__ W2l, const void* __restrict__ W2r,
    const void* __restrict__ b2, void* __restrict__ out,
    const int* __restrict__ flags, int nn) {
    __shared__ u16 wt_s[64][264];    // [n][k]; k 0..127 W2l, 128..255 W2r
    __shared__ u16 in_s[32][264];    // [m][k]; k 0..127 mean, 128..255 h
    __shared__ float b_s[64];
    int tid = threadIdx.x;
    int node0 = blockIdx.x * 32;
    int obf = flags[0];

    // ---- stage weights transposed ----
    // W2l global: [128 k][64 n]; ushort4 i -> k=i>>4, n=(i&15)*4.
    if (flags[4]) {
        const ushort4* s = (const ushort4*)W2l;
        for (int i = tid; i < 2048; i += 512) {
            ushort4 v = s[i]; int k = i >> 4, n = (i & 15) * 4;
            wt_s[n + 0][k] = v.x; wt_s[n + 1][k] = v.y;
            wt_s[n + 2][k] = v.z; wt_s[n + 3][k] = v.w;
        }
    } else {
        const float4* s = (const float4*)W2l;
        for (int i = tid; i < 2048; i += 512) {
            float4 f = s[i]; int k = i >> 4, n = (i & 15) * 4;
            wt_s[n + 0][k] = f2bf(f.x); wt_s[n + 1][k] = f2bf(f.y);
            wt_s[n + 2][k] = f2bf(f.z); wt_s[n + 3][k] = f2bf(f.w);
        }
    }
    if (flags[5]) {
        const ushort4* s = (const ushort4*)W2r;
        for (int i = tid; i < 2048; i += 512) {
            ushort4 v = s[i]; int k = 128 + (i >> 4), n = (i & 15) * 4;
            wt_s[n + 0][k] = v.x; wt_s[n + 1][k] = v.y;
            wt_s[n + 2][k] = v.z; wt_s[n + 3][k] = v.w;
        }
    } else {
        const float4* s = (const float4*)W2r;
        for (int i = tid; i < 2048; i += 512) {
            float4 f = s[i]; int k = 128 + (i >> 4), n = (i & 15) * 4;
            wt_s[n + 0][k] = f2bf(f.x); wt_s[n + 1][k] = f2bf(f.y);
            wt_s[n + 2][k] = f2bf(f.z); wt_s[n + 3][k] = f2bf(f.w);
        }
    }
    if (tid < 64) b_s[tid] = flags[6] ? bf2f(((const u16*)b2)[tid]) : ((const float*)b2)[tid];

    // ---- gather-mean phase (16 lanes/node, 8 feats/lane, unroll x8) ----
    int grp = tid >> 4, gl = tid & 15;
    int n = node0 + grp;
    if (n < nn) {
        int beg = off[n], deg = cnt[n];
        float a[8];
#pragma unroll
        for (int j = 0; j < 8; j++) a[j] = 0.0f;
        const u16* hb = h + (size_t)gl * 8;
        int i = 0;
        for (; i + 8 <= deg; i += 8) {
            uint4 v[8];
#pragma unroll
            for (int j = 0; j < 8; j++) {
                int s0 = esrc[beg + i + j];
                v[j] = *(const uint4*)(hb + (size_t)s0 * 128);
            }
#pragma unroll
            for (int j = 0; j < 8; j++) {
                a[0] += bfu_lo(v[j].x); a[1] += bfu_hi(v[j].x);
                a[2] += bfu_lo(v[j].y); a[3] += bfu_hi(v[j].y);
                a[4] += bfu_lo(v[j].z); a[5] += bfu_hi(v[j].z);
                a[6] += bfu_lo(v[j].w); a[7] += bfu_hi(v[j].w);
            }
        }
        for (; i < deg; i++) {
            int s0 = esrc[beg + i];
            uint4 v = *(const uint4*)(hb + (size_t)s0 * 128);
            a[0] += bfu_lo(v.x); a[1] += bfu_hi(v.x);
            a[2] += bfu_lo(v.y); a[3] += bfu_hi(v.y);
            a[4] += bfu_lo(v.z); a[5] += bfu_hi(v.z);
            a[6] += bfu_lo(v.w); a[7] += bfu_hi(v.w);
        }
        float inv = 1.0f / (float)(deg > 0 ? deg : 1);
        *(ushort4*)&in_s[grp][gl * 8] =
            make_ushort4(f2bf(a[0] * inv), f2bf(a[1] * inv), f2bf(a[2] * inv), f2bf(a[3] * inv));
        *(ushort4*)&in_s[grp][gl * 8 + 4] =
            make_ushort4(f2bf(a[4] * inv), f2bf(a[5] * inv), f2bf(a[6] * inv), f2bf(a[7] * inv));
        uint4 hv = *(const uint4*)(h + (size_t)n * 128 + gl * 8);
        *(uint4*)&in_s[grp][128 + gl * 8] = hv;
    } else {
        *(ushort4*)&in_s[grp][gl * 8] = make_ushort4(0, 0, 0, 0);
        *(ushort4*)&in_s[grp][gl * 8 + 4] = make_ushort4(0, 0, 0, 0);
        *(uint4*)&in_s[grp][128 + gl * 8] = make_uint4(0, 0, 0, 0);
    }
    __syncthreads();

    // ---- MFMA phase ----
    int wv = tid >> 6, lane = tid & 63;
    int l15 = lane & 15, q = lane >> 4;
    int m0 = (wv >> 2) * 16, n0 = (wv & 3) * 16;
    f32x4 acc = {0.f, 0.f, 0.f, 0.f};
    const u16* arow = &in_s[m0 + l15][q * 8];
    const u16* brow = &wt_s[n0 + l15][q * 8];
#pragma unroll
    for (int kc = 0; kc < 8; kc++) {
        short8 a = *(const short8*)(arow + kc * 32);
        short8 b = *(const short8*)(brow + kc * 32);
        acc = __builtin_amdgcn_mfma_f32_16x16x32_bf16(a, b, acc, 0, 0, 0);
    }
    int nc = n0 + l15;
    float bias = b_s[nc];
#pragma unroll
    for (int r = 0; r < 4; r++) {
        int m = q * 4 + r;
        int nd = node0 + m0 + m;
        if (nd < nn) {
            float v = acc[r] + bias;
            if (obf) ((u16*)out)[(size_t)nd * 64 + nc] = f2bf(v);
            else     ((float*)out)[(size_t)nd * 64 + nc] = v;
        }
    }
}

// ---------------- fallback ----------------
__global__ __launch_bounds__(256) void zero_out_k(u16* __restrict__ out, int n) {
    int i = blockIdx.x * 256 + threadIdx.x;
    if (i < n) out[i] = 0;
}

extern "C" void kernel_launch(void* const* d_in, const int* in_sizes, int n_in,
                              void* d_out, int out_size, void* d_ws, size_t ws_size,
                              hipStream_t stream) {
    const void* x   = d_in[0];
    const void* ei  = d_in[1];
    const void* W1l = d_in[2];
    const void* W1r = d_in[3];
    const void* b1  = d_in[4];
    const void* W2l = d_in[5];
    const void* W2r = d_in[6];
    const void* b2  = d_in[7];

    int nn = in_sizes[0] / 64;
    int ne = in_sizes[1] / 2;
    int nblk = (nn + 1023) / 1024;

    auto al = [](size_t v) { return (v + 255) & ~(size_t)255; };
    size_t o_flags = 0;
    size_t o_cnt   = 256;
    size_t o_off   = al(o_cnt + (size_t)nn * 4);
    size_t o_cur   = al(o_off + (size_t)nn * 4);
    size_t o_part  = al(o_cur + (size_t)nn * 4);
    size_t o_esrc  = al(o_part + 4096);
    size_t o_h     = al(o_esrc + (size_t)ne * 4);
    size_t ws_req  = o_h + (size_t)nn * 128 * 2;

    if (ws_size < ws_req || nblk > 1024) {
        zero_out_k<<<(out_size + 255) / 256, 256, 0, stream>>>((u16*)d_out, out_size);
        return;
    }

    char* ws = (char*)d_ws;
    int* flags    = (int*)(ws + o_flags);
    int* cnt      = (int*)(ws + o_cnt);
    int* off      = (int*)(ws + o_off);
    int* cur      = (int*)(ws + o_cur);
    int* partials = (int*)(ws + o_part);
    int* esrc     = (int*)(ws + o_esrc);
    u16* h        = (u16*)(ws + o_h);

    probe_k<<<1, 256, 0, stream>>>(x, W1l, W1r, b1, W2l, W2r, b2, ei, flags, ne,
                                   in_sizes[0], in_sizes[2], in_sizes[3], in_sizes[4],
                                   in_sizes[5], in_sizes[6], in_sizes[7]);
    hipMemsetAsync(cnt, 0, (size_t)nn * 4, stream);
    count_deg<<<(ne + 255) / 256, 256, 0, stream>>>(ei, cnt, flags, nn, ne);
    scan_local<<<nblk, 256, 0, stream>>>(cnt, off, partials, nn);
    scan_partials<<<1, 1024, 0, stream>>>(partials, nblk);
    scan_addback<<<nblk, 256, 0, stream>>>(off, cur, partials, nn);
    fill_csr<<<(ne + 255) / 256, 256, 0, stream>>>(ei, cur, esrc, flags, nn, ne);
    int lb = (nn + 31) / 32;
    layer1<<<lb, 512, 0, stream>>>(x, esrc, off, cnt, W1l, W1r, b1, h, flags, nn);
    layer2<<<lb, 512, 0, stream>>>(h, esrc, off, cnt, W2l, W2r, b2, d_out, flags, nn);
}

// Round 7
// 323.634 us; speedup vs baseline: 2.2516x; 1.3756x over previous
//
#include <hip/hip_runtime.h>
#include <hip/hip_bf16.h>
#include <stdint.h>

// GraphSAGE 2-layer encoder — bucketed CSR build + MFMA GEMM layers.
// R7 = R6 resubmit (container infra failure, no bench signal).
//   bucket_count : LDS hist of dst>>9 (~196 buckets), ~100K global atomics
//   scan_buckets : 196-entry scan -> bo[], bcur[]
//   partition_k  : chunk=8192 edges, LDS-grouped, coalesced run copy-out (packed)
//   csr_fill2    : 1 block/bucket: LDS hist+scan -> off/cnt (coalesced) + esrc
//                  scatter confined to 32KB single-block region
// Packed edge buffer (ne*4 B) aliases h region (written later by layer1).

typedef unsigned short u16;
typedef __attribute__((ext_vector_type(8))) short short8;   // bf16x8 A/B frag
typedef __attribute__((ext_vector_type(4))) float f32x4;    // fp32x4 C/D frag

#define BSHIFT 9
#define BSIZE  512          // nodes per bucket
#define CHUNK  8192         // edges per partition block

__device__ __forceinline__ float bf2f(u16 v) { return __uint_as_float(((uint32_t)v) << 16); }
__device__ __forceinline__ float bfu_lo(uint32_t u) { return __uint_as_float(u << 16); }
__device__ __forceinline__ float bfu_hi(uint32_t u) { return __uint_as_float(u & 0xffff0000u); }
__device__ __forceinline__ u16 f2bf(float f) {
    uint32_t u = __float_as_uint(f);
    return (u16)((u + 0x7fffu + ((u >> 16) & 1u)) >> 16);
}

// ---------------- probe: dtype flags ----------------
// flags[0..6]: 1 if float array i is bf16, 0 if fp32 (x,W1l,W1r,b1,W2l,W2r,b2)
// flags[7]:    1 if edge_index is int64, 0 if int32
__global__ __launch_bounds__(256) void probe_k(
    const void* x, const void* w1l, const void* w1r, const void* b1,
    const void* w2l, const void* w2r, const void* b2, const void* ei,
    int* __restrict__ flags, int ne,
    int c0, int c1, int c2, int c3, int c4, int c5, int c6) {
    __shared__ int cs_s[8];
    int tid = threadIdx.x, a = tid >> 5, lane = tid & 31;
    if (tid < 8) cs_s[tid] = 0;
    __syncthreads();
    if (a < 7) {
        const void* ptrs[7] = {x, w1l, w1r, b1, w2l, w2r, b2};
        int cs[7] = {c0, c1, c2, c3, c4, c5, c6};
        int C = cs[a];
        int stride = C / 32; if (stride < 1) stride = 1;
        long long i = (long long)lane * stride;
        if (i > C - 1) i = C - 1;
        i &= ~1LL;                       // even index: fp32 low-half if fp32
        u16 v = ((const u16*)ptrs[a])[i];
        int e = (v >> 7) & 0xFF;
        int sane = ((e >= 0x50 && e <= 0x97) || v == 0) ? 1 : 0;
        atomicAdd(&cs_s[a], sane);
    } else {
        long long n32 = 2LL * ne;
        long long stride = n32 / 32; if (stride < 1) stride = 1;
        long long i = (long long)lane * stride; i |= 1;   // odd word
        if (i >= n32) i = 1;
        int wv = ((const int*)ei)[i];
        atomicAdd(&cs_s[7], wv != 0 ? 1 : 0);
    }
    __syncthreads();
    if (tid < 7) flags[tid] = (cs_s[tid] >= 24) ? 1 : 0;
    if (tid == 7) flags[7] = (cs_s[7] == 0) ? 1 : 0;
}

// ---------------- bucket histogram ----------------
__global__ __launch_bounds__(256) void bucket_count(
    const void* __restrict__ ei, int* __restrict__ bcnt,
    const int* __restrict__ flags, int nn, int ne, int nb) {
    __shared__ int hist[512];
    for (int i = threadIdx.x; i < 512; i += 256) hist[i] = 0;
    __syncthreads();
    int e64 = flags[7];
    int stride = gridDim.x * 256;
    for (int e = blockIdx.x * 256 + threadIdx.x; e < ne; e += stride) {
        int dst = e64 ? (int)((const long long*)ei)[(size_t)ne + e]
                      : ((const int*)ei)[(size_t)ne + e];
        if ((unsigned)dst < (unsigned)nn) atomicAdd(&hist[dst >> BSHIFT], 1);
    }
    __syncthreads();
    for (int i = threadIdx.x; i < nb; i += 256)
        if (hist[i]) atomicAdd(&bcnt[i], hist[i]);
}

// ---------------- bucket scan ----------------
__global__ __launch_bounds__(64) void scan_buckets(
    const int* __restrict__ bcnt, int* __restrict__ bo,
    int* __restrict__ bcur, int nb) {
    if (threadIdx.x == 0) {
        int s = 0;
        for (int b = 0; b < nb; b++) { bo[b] = s; bcur[b] = s; s += bcnt[b]; }
        bo[nb] = s;
    }
}

// ---------------- partition: bucket-grouped packed edges ----------------
// 512 thr x 16 edges = 8192/chunk. Pack: src (17b) | dstlo (9b) << 17.
__global__ __launch_bounds__(512) void partition_k(
    const void* __restrict__ ei, int* __restrict__ bcur,
    unsigned* __restrict__ ep, const int* __restrict__ flags,
    int nn, int ne, int nb) {
    __shared__ unsigned stage[CHUNK];    // 32 KB
    __shared__ u16 ab[CHUNK];            // 16 KB
    __shared__ int hist[512], scanv[512], gbase[512], lcur[512];
    int tid = threadIdx.x;
    int base = blockIdx.x * CHUNK;
    for (int i = tid; i < 512; i += 512) { hist[i] = 0; }
    __syncthreads();
    int e64 = flags[7];
    unsigned pk[16]; int bk[16];
#pragma unroll
    for (int j = 0; j < 16; j++) {
        int e = base + j * 512 + tid;
        bk[j] = -1;
        pk[j] = 0;
        if (e < ne) {
            int src, dst;
            if (e64) {
                src = (int)((const long long*)ei)[e];
                dst = (int)((const long long*)ei)[(size_t)ne + e];
            } else {
                src = ((const int*)ei)[e];
                dst = ((const int*)ei)[(size_t)ne + e];
            }
            if ((unsigned)dst < (unsigned)nn) {
                if ((unsigned)src >= (unsigned)nn) src = 0;
                bk[j] = dst >> BSHIFT;
                pk[j] = (unsigned)src | ((unsigned)(dst & (BSIZE - 1)) << 17);
                atomicAdd(&hist[bk[j]], 1);
            }
        }
    }
    __syncthreads();
    if (tid == 0) {
        int s = 0;
        for (int b = 0; b < nb; b++) { scanv[b] = s; s += hist[b]; }
    }
    __syncthreads();
    for (int b = tid; b < nb; b += 512) {
        lcur[b] = scanv[b];
        gbase[b] = hist[b] ? atomicAdd(&bcur[b], hist[b]) : 0;
    }
    __syncthreads();
#pragma unroll
    for (int j = 0; j < 16; j++) {
        if (bk[j] >= 0) {
            int r = atomicAdd(&lcur[bk[j]], 1);
            stage[r] = pk[j];
            ab[r] = (u16)bk[j];
        }
    }
    __syncthreads();
    int tot = scanv[nb - 1] + hist[nb - 1];
    for (int j = tid; j < tot; j += 512) {
        int b = ab[j];
        ep[gbase[b] + (j - scanv[b])] = stage[j];
    }
}

// ---------------- per-bucket CSR finalize ----------------
// 1 block per bucket: hist+scan -> off/cnt (coalesced), esrc scatter in-block.
__global__ __launch_bounds__(512) void csr_fill2(
    const unsigned* __restrict__ ep, const int* __restrict__ bo,
    int* __restrict__ off, int* __restrict__ cnt, int* __restrict__ esrc,
    int nn) {
    __shared__ int hist[BSIZE], loff[BSIZE], lcur[BSIZE];
    int b = blockIdx.x;
    int beg = bo[b], end = bo[b + 1];
    int tid = threadIdx.x;
    hist[tid] = 0;
    __syncthreads();
    for (int j = beg + tid; j < end; j += 512)
        atomicAdd(&hist[(ep[j] >> 17) & (BSIZE - 1)], 1);
    __syncthreads();
    if (tid == 0) {
        int s = beg;
        for (int i = 0; i < BSIZE; i++) { loff[i] = s; s += hist[i]; }
    }
    __syncthreads();
    lcur[tid] = loff[tid];
    int node = b * BSIZE + tid;
    if (node < nn) { off[node] = loff[tid]; cnt[node] = hist[tid]; }
    __syncthreads();
    for (int j = beg + tid; j < end; j += 512) {
        unsigned p = ep[j];
        int r = atomicAdd(&lcur[(p >> 17) & (BSIZE - 1)], 1);
        esrc[r] = (int)(p & 0x1FFFFu);
    }
}

// ---------------- layer 1 ----------------
// 512 thr = 32 nodes x 16 lanes (gather) = 8 waves (MFMA).
// Tile: M=32, N=128, K=128. Wave w: n0=w*16, both m-tiles (0,16). 4 K-chunks.
__global__ __launch_bounds__(512, 4) void layer1(
    const void* __restrict__ x, const int* __restrict__ esrc,
    const int* __restrict__ off, const int* __restrict__ cnt,
    const void* __restrict__ W1l, const void* __restrict__ W1r,
    const void* __restrict__ b1, u16* __restrict__ h,
    const int* __restrict__ flags, int nn) {
    __shared__ u16 wt_s[128][136];   // [n][k] transposed; k 0..63 W1l, 64..127 W1r
    __shared__ u16 in_s[32][136];    // [m][k]; k 0..63 mean, 64..127 x
    __shared__ float b_s[128];
    int tid = threadIdx.x;
    int node0 = blockIdx.x * 32;
    int xbf = flags[0];

    if (flags[1]) {
        const ushort4* s = (const ushort4*)W1l;
        for (int i = tid; i < 2048; i += 512) {
            ushort4 v = s[i]; int k = i >> 5, n = (i & 31) * 4;
            wt_s[n + 0][k] = v.x; wt_s[n + 1][k] = v.y;
            wt_s[n + 2][k] = v.z; wt_s[n + 3][k] = v.w;
        }
    } else {
        const float4* s = (const float4*)W1l;
        for (int i = tid; i < 2048; i += 512) {
            float4 f = s[i]; int k = i >> 5, n = (i & 31) * 4;
            wt_s[n + 0][k] = f2bf(f.x); wt_s[n + 1][k] = f2bf(f.y);
            wt_s[n + 2][k] = f2bf(f.z); wt_s[n + 3][k] = f2bf(f.w);
        }
    }
    if (flags[2]) {
        const ushort4* s = (const ushort4*)W1r;
        for (int i = tid; i < 2048; i += 512) {
            ushort4 v = s[i]; int k = 64 + (i >> 5), n = (i & 31) * 4;
            wt_s[n + 0][k] = v.x; wt_s[n + 1][k] = v.y;
            wt_s[n + 2][k] = v.z; wt_s[n + 3][k] = v.w;
        }
    } else {
        const float4* s = (const float4*)W1r;
        for (int i = tid; i < 2048; i += 512) {
            float4 f = s[i]; int k = 64 + (i >> 5), n = (i & 31) * 4;
            wt_s[n + 0][k] = f2bf(f.x); wt_s[n + 1][k] = f2bf(f.y);
            wt_s[n + 2][k] = f2bf(f.z); wt_s[n + 3][k] = f2bf(f.w);
        }
    }
    if (tid < 128) b_s[tid] = flags[3] ? bf2f(((const u16*)b1)[tid]) : ((const float*)b1)[tid];

    int grp = tid >> 4, gl = tid & 15;
    int n = node0 + grp;
    if (n < nn) {
        int beg = off[n], deg = cnt[n];
        float a0 = 0.f, a1 = 0.f, a2 = 0.f, a3 = 0.f;
        int i = 0;
        if (xbf) {
            const u16* xb = (const u16*)x + gl * 4;
            for (; i + 8 <= deg; i += 8) {
                ushort4 v[8];
#pragma unroll
                for (int j = 0; j < 8; j++) {
                    int s0 = esrc[beg + i + j];
                    v[j] = *(const ushort4*)(xb + (size_t)s0 * 64);
                }
#pragma unroll
                for (int j = 0; j < 8; j++) {
                    a0 += bf2f(v[j].x); a1 += bf2f(v[j].y);
                    a2 += bf2f(v[j].z); a3 += bf2f(v[j].w);
                }
            }
            for (; i < deg; i++) {
                int s0 = esrc[beg + i];
                ushort4 v = *(const ushort4*)(xb + (size_t)s0 * 64);
                a0 += bf2f(v.x); a1 += bf2f(v.y); a2 += bf2f(v.z); a3 += bf2f(v.w);
            }
        } else {
            const float* xb = (const float*)x + gl * 4;
            for (; i + 8 <= deg; i += 8) {
                float4 v[8];
#pragma unroll
                for (int j = 0; j < 8; j++) {
                    int s0 = esrc[beg + i + j];
                    v[j] = *(const float4*)(xb + (size_t)s0 * 64);
                }
#pragma unroll
                for (int j = 0; j < 8; j++) {
                    a0 += v[j].x; a1 += v[j].y; a2 += v[j].z; a3 += v[j].w;
                }
            }
            for (; i < deg; i++) {
                int s0 = esrc[beg + i];
                float4 v = *(const float4*)(xb + (size_t)s0 * 64);
                a0 += v.x; a1 += v.y; a2 += v.z; a3 += v.w;
            }
        }
        float inv = 1.0f / (float)(deg > 0 ? deg : 1);
        *(ushort4*)&in_s[grp][gl * 4] =
            make_ushort4(f2bf(a0 * inv), f2bf(a1 * inv), f2bf(a2 * inv), f2bf(a3 * inv));
        if (xbf) {
            *(ushort4*)&in_s[grp][64 + gl * 4] =
                *(const ushort4*)((const u16*)x + (size_t)n * 64 + gl * 4);
        } else {
            float4 xv = *(const float4*)((const float*)x + (size_t)n * 64 + gl * 4);
            *(ushort4*)&in_s[grp][64 + gl * 4] =
                make_ushort4(f2bf(xv.x), f2bf(xv.y), f2bf(xv.z), f2bf(xv.w));
        }
    } else {
        *(ushort4*)&in_s[grp][gl * 4] = make_ushort4(0, 0, 0, 0);
        *(ushort4*)&in_s[grp][64 + gl * 4] = make_ushort4(0, 0, 0, 0);
    }
    __syncthreads();

    int wv = tid >> 6, lane = tid & 63;
    int l15 = lane & 15, q = lane >> 4;
    int n0 = wv * 16;
    f32x4 acc0 = {0.f, 0.f, 0.f, 0.f};
    f32x4 acc1 = {0.f, 0.f, 0.f, 0.f};
    const u16* arow0 = &in_s[l15][q * 8];
    const u16* arow1 = &in_s[16 + l15][q * 8];
    const u16* brow  = &wt_s[n0 + l15][q * 8];
#pragma unroll
    for (int kc = 0; kc < 4; kc++) {
        short8 a0 = *(const short8*)(arow0 + kc * 32);
        short8 a1 = *(const short8*)(arow1 + kc * 32);
        short8 b  = *(const short8*)(brow  + kc * 32);
        acc0 = __builtin_amdgcn_mfma_f32_16x16x32_bf16(a0, b, acc0, 0, 0, 0);
        acc1 = __builtin_amdgcn_mfma_f32_16x16x32_bf16(a1, b, acc1, 0, 0, 0);
    }
    int nc = n0 + l15;
    float bias = b_s[nc];
#pragma unroll
    for (int r = 0; r < 4; r++) {
        int m = q * 4 + r;
        int nd = node0 + m;
        if (nd < nn) h[(size_t)nd * 128 + nc] = f2bf(fmaxf(acc0[r] + bias, 0.0f));
        nd = node0 + 16 + m;
        if (nd < nn) h[(size_t)nd * 128 + nc] = f2bf(fmaxf(acc1[r] + bias, 0.0f));
    }
}

// ---------------- layer 2 ----------------
// 512 thr = 32 nodes x 16 lanes (gather) = 8 waves (MFMA).
// Tile: M=32, N=64, K=256. Wave w: m0=(w>>2)*16, n0=(w&3)*16. 8 K-chunks.
__global__ __launch_bounds__(512, 4) void layer2(
    const u16* __restrict__ h, const int* __restrict__ esrc,
    const int* __restrict__ off, const int* __restrict__ cnt,
    const void* __restrict__ W2l, const void* __restrict__ W2r,
    const void* __restrict__ b2, void* __restrict__ out,
    const int* __restrict__ flags, int nn) {
    __shared__ u16 wt_s[64][264];    // [n][k]; k 0..127 W2l, 128..255 W2r
    __shared__ u16 in_s[32][264];    // [m][k]; k 0..127 mean, 128..255 h
    __shared__ float b_s[64];
    int tid = threadIdx.x;
    int node0 = blockIdx.x * 32;
    int obf = flags[0];

    if (flags[4]) {
        const ushort4* s = (const ushort4*)W2l;
        for (int i = tid; i < 2048; i += 512) {
            ushort4 v = s[i]; int k = i >> 4, n = (i & 15) * 4;
            wt_s[n + 0][k] = v.x; wt_s[n + 1][k] = v.y;
            wt_s[n + 2][k] = v.z; wt_s[n + 3][k] = v.w;
        }
    } else {
        const float4* s = (const float4*)W2l;
        for (int i = tid; i < 2048; i += 512) {
            float4 f = s[i]; int k = i >> 4, n = (i & 15) * 4;
            wt_s[n + 0][k] = f2bf(f.x); wt_s[n + 1][k] = f2bf(f.y);
            wt_s[n + 2][k] = f2bf(f.z); wt_s[n + 3][k] = f2bf(f.w);
        }
    }
    if (flags[5]) {
        const ushort4* s = (const ushort4*)W2r;
        for (int i = tid; i < 2048; i += 512) {
            ushort4 v = s[i]; int k = 128 + (i >> 4), n = (i & 15) * 4;
            wt_s[n + 0][k] = v.x; wt_s[n + 1][k] = v.y;
            wt_s[n + 2][k] = v.z; wt_s[n + 3][k] = v.w;
        }
    } else {
        const float4* s = (const float4*)W2r;
        for (int i = tid; i < 2048; i += 512) {
            float4 f = s[i]; int k = 128 + (i >> 4), n = (i & 15) * 4;
            wt_s[n + 0][k] = f2bf(f.x); wt_s[n + 1][k] = f2bf(f.y);
            wt_s[n + 2][k] = f2bf(f.z); wt_s[n + 3][k] = f2bf(f.w);
        }
    }
    if (tid < 64) b_s[tid] = flags[6] ? bf2f(((const u16*)b2)[tid]) : ((const float*)b2)[tid];

    int grp = tid >> 4, gl = tid & 15;
    int n = node0 + grp;
    if (n < nn) {
        int beg = off[n], deg = cnt[n];
        float a[8];
#pragma unroll
        for (int j = 0; j < 8; j++) a[j] = 0.0f;
        const u16* hb = h + (size_t)gl * 8;
        int i = 0;
        for (; i + 8 <= deg; i += 8) {
            uint4 v[8];
#pragma unroll
            for (int j = 0; j < 8; j++) {
                int s0 = esrc[beg + i + j];
                v[j] = *(const uint4*)(hb + (size_t)s0 * 128);
            }
#pragma unroll
            for (int j = 0; j < 8; j++) {
                a[0] += bfu_lo(v[j].x); a[1] += bfu_hi(v[j].x);
                a[2] += bfu_lo(v[j].y); a[3] += bfu_hi(v[j].y);
                a[4] += bfu_lo(v[j].z); a[5] += bfu_hi(v[j].z);
                a[6] += bfu_lo(v[j].w); a[7] += bfu_hi(v[j].w);
            }
        }
        for (; i < deg; i++) {
            int s0 = esrc[beg + i];
            uint4 v = *(const uint4*)(hb + (size_t)s0 * 128);
            a[0] += bfu_lo(v.x); a[1] += bfu_hi(v.x);
            a[2] += bfu_lo(v.y); a[3] += bfu_hi(v.y);
            a[4] += bfu_lo(v.z); a[5] += bfu_hi(v.z);
            a[6] += bfu_lo(v.w); a[7] += bfu_hi(v.w);
        }
        float inv = 1.0f / (float)(deg > 0 ? deg : 1);
        *(ushort4*)&in_s[grp][gl * 8] =
            make_ushort4(f2bf(a[0] * inv), f2bf(a[1] * inv), f2bf(a[2] * inv), f2bf(a[3] * inv));
        *(ushort4*)&in_s[grp][gl * 8 + 4] =
            make_ushort4(f2bf(a[4] * inv), f2bf(a[5] * inv), f2bf(a[6] * inv), f2bf(a[7] * inv));
        uint4 hv = *(const uint4*)(h + (size_t)n * 128 + gl * 8);
        *(uint4*)&in_s[grp][128 + gl * 8] = hv;
    } else {
        *(ushort4*)&in_s[grp][gl * 8] = make_ushort4(0, 0, 0, 0);
        *(ushort4*)&in_s[grp][gl * 8 + 4] = make_ushort4(0, 0, 0, 0);
        *(uint4*)&in_s[grp][128 + gl * 8] = make_uint4(0, 0, 0, 0);
    }
    __syncthreads();

    int wv = tid >> 6, lane = tid & 63;
    int l15 = lane & 15, q = lane >> 4;
    int m0 = (wv >> 2) * 16, n0 = (wv & 3) * 16;
    f32x4 acc = {0.f, 0.f, 0.f, 0.f};
    const u16* arow = &in_s[m0 + l15][q * 8];
    const u16* brow = &wt_s[n0 + l15][q * 8];
#pragma unroll
    for (int kc = 0; kc < 8; kc++) {
        short8 a = *(const short8*)(arow + kc * 32);
        short8 b = *(const short8*)(brow + kc * 32);
        acc = __builtin_amdgcn_mfma_f32_16x16x32_bf16(a, b, acc, 0, 0, 0);
    }
    int nc = n0 + l15;
    float bias = b_s[nc];
#pragma unroll
    for (int r = 0; r < 4; r++) {
        int m = q * 4 + r;
        int nd = node0 + m0 + m;
        if (nd < nn) {
            float v = acc[r] + bias;
            if (obf) ((u16*)out)[(size_t)nd * 64 + nc] = f2bf(v);
            else     ((float*)out)[(size_t)nd * 64 + nc] = v;
        }
    }
}

// ---------------- fallback ----------------
__global__ __launch_bounds__(256) void zero_out_k(u16* __restrict__ out, int n) {
    int i = blockIdx.x * 256 + threadIdx.x;
    if (i < n) out[i] = 0;
}

extern "C" void kernel_launch(void* const* d_in, const int* in_sizes, int n_in,
                              void* d_out, int out_size, void* d_ws, size_t ws_size,
                              hipStream_t stream) {
    const void* x   = d_in[0];
    const void* ei  = d_in[1];
    const void* W1l = d_in[2];
    const void* W1r = d_in[3];
    const void* b1  = d_in[4];
    const void* W2l = d_in[5];
    const void* W2r = d_in[6];
    const void* b2  = d_in[7];

    int nn = in_sizes[0] / 64;
    int ne = in_sizes[1] / 2;
    int nb = (nn + BSIZE - 1) / BSIZE;

    auto al = [](size_t v) { return (v + 255) & ~(size_t)255; };
    size_t o_flags = 0;
    size_t o_bcnt  = 256;
    size_t o_bo    = al(o_bcnt + 512 * 4);
    size_t o_bcur  = al(o_bo + 513 * 4);
    size_t o_cnt   = al(o_bcur + 512 * 4);
    size_t o_off   = al(o_cnt + (size_t)nn * 4);
    size_t o_esrc  = al(o_off + (size_t)nn * 4);
    size_t o_h     = al(o_esrc + (size_t)ne * 4);
    size_t ws_req  = o_h + (size_t)nn * 128 * 2;

    // ep (packed edges, ne*4 B) aliases the h region (h written after csr_fill2)
    bool ok = ws_size >= ws_req && nb >= 1 && nb <= 512 && nn <= 131072 &&
              (size_t)ne * 4 <= (size_t)nn * 256;
    if (!ok) {
        zero_out_k<<<(out_size + 255) / 256, 256, 0, stream>>>((u16*)d_out, out_size);
        return;
    }

    char* ws = (char*)d_ws;
    int* flags = (int*)(ws + o_flags);
    int* bcnt  = (int*)(ws + o_bcnt);
    int* bo    = (int*)(ws + o_bo);
    int* bcur  = (int*)(ws + o_bcur);
    int* cnt   = (int*)(ws + o_cnt);
    int* off   = (int*)(ws + o_off);
    int* esrc  = (int*)(ws + o_esrc);
    u16* h     = (u16*)(ws + o_h);
    unsigned* ep = (unsigned*)(ws + o_h);

    probe_k<<<1, 256, 0, stream>>>(x, W1l, W1r, b1, W2l, W2r, b2, ei, flags, ne,
                                   in_sizes[0], in_sizes[2], in_sizes[3], in_sizes[4],
                                   in_sizes[5], in_sizes[6], in_sizes[7]);
    hipMemsetAsync(bcnt, 0, 512 * 4, stream);
    bucket_count<<<512, 256, 0, stream>>>(ei, bcnt, flags, nn, ne, nb);
    scan_buckets<<<1, 64, 0, stream>>>(bcnt, bo, bcur, nb);
    int nchunk = (ne + CHUNK - 1) / CHUNK;
    partition_k<<<nchunk, 512, 0, stream>>>(ei, bcur, ep, flags, nn, ne, nb);
    csr_fill2<<<nb, 512, 0, stream>>>(ep, bo, off, cnt, esrc, nn);
    int lb = (nn + 31) / 32;
    layer1<<<lb, 512, 0, stream>>>(x, esrc, off, cnt, W1l, W1r, b1, h, flags, nn);
    layer2<<<lb, 512, 0, stream>>>(h, esrc, off, cnt, W2l, W2r, b2, d_out, flags, nn);
}

// Round 8
// 306.496 us; speedup vs baseline: 2.3775x; 1.0559x over previous
//
#include <hip/hip_runtime.h>
#include <hip/hip_bf16.h>
#include <stdint.h>

// GraphSAGE 2-layer encoder — bucketed CSR build + MFMA GEMM layers.
// R8: fragment-major LDS layout for MFMA operands (conflict-free ds_read_b128
// at chunk_base + lane*16); parallel Hillis-Steele scans in partition/csr/bucket.

typedef unsigned short u16;
typedef __attribute__((ext_vector_type(8))) short short8;   // bf16x8 A/B frag
typedef __attribute__((ext_vector_type(4))) float f32x4;    // fp32x4 C/D frag

#define BSHIFT 9
#define BSIZE  512          // nodes per bucket
#define CHUNK  8192         // edges per partition block

__device__ __forceinline__ float bf2f(u16 v) { return __uint_as_float(((uint32_t)v) << 16); }
__device__ __forceinline__ float bfu_lo(uint32_t u) { return __uint_as_float(u << 16); }
__device__ __forceinline__ float bfu_hi(uint32_t u) { return __uint_as_float(u & 0xffff0000u); }
__device__ __forceinline__ u16 f2bf(float f) {
    uint32_t u = __float_as_uint(f);
    return (u16)((u + 0x7fffu + ((u >> 16) & 1u)) >> 16);
}

// ---------------- probe: dtype flags ----------------
__global__ __launch_bounds__(256) void probe_k(
    const void* x, const void* w1l, const void* w1r, const void* b1,
    const void* w2l, const void* w2r, const void* b2, const void* ei,
    int* __restrict__ flags, int ne,
    int c0, int c1, int c2, int c3, int c4, int c5, int c6) {
    __shared__ int cs_s[8];
    int tid = threadIdx.x, a = tid >> 5, lane = tid & 31;
    if (tid < 8) cs_s[tid] = 0;
    __syncthreads();
    if (a < 7) {
        const void* ptrs[7] = {x, w1l, w1r, b1, w2l, w2r, b2};
        int cs[7] = {c0, c1, c2, c3, c4, c5, c6};
        int C = cs[a];
        int stride = C / 32; if (stride < 1) stride = 1;
        long long i = (long long)lane * stride;
        if (i > C - 1) i = C - 1;
        i &= ~1LL;
        u16 v = ((const u16*)ptrs[a])[i];
        int e = (v >> 7) & 0xFF;
        int sane = ((e >= 0x50 && e <= 0x97) || v == 0) ? 1 : 0;
        atomicAdd(&cs_s[a], sane);
    } else {
        long long n32 = 2LL * ne;
        long long stride = n32 / 32; if (stride < 1) stride = 1;
        long long i = (long long)lane * stride; i |= 1;
        if (i >= n32) i = 1;
        int wv = ((const int*)ei)[i];
        atomicAdd(&cs_s[7], wv != 0 ? 1 : 0);
    }
    __syncthreads();
    if (tid < 7) flags[tid] = (cs_s[tid] >= 24) ? 1 : 0;
    if (tid == 7) flags[7] = (cs_s[7] == 0) ? 1 : 0;
}

// ---------------- bucket histogram ----------------
__global__ __launch_bounds__(256) void bucket_count(
    const void* __restrict__ ei, int* __restrict__ bcnt,
    const int* __restrict__ flags, int nn, int ne, int nb) {
    __shared__ int hist[512];
    for (int i = threadIdx.x; i < 512; i += 256) hist[i] = 0;
    __syncthreads();
    int e64 = flags[7];
    int stride = gridDim.x * 256;
    for (int e = blockIdx.x * 256 + threadIdx.x; e < ne; e += stride) {
        int dst = e64 ? (int)((const long long*)ei)[(size_t)ne + e]
                      : ((const int*)ei)[(size_t)ne + e];
        if ((unsigned)dst < (unsigned)nn) atomicAdd(&hist[dst >> BSHIFT], 1);
    }
    __syncthreads();
    for (int i = threadIdx.x; i < nb; i += 256)
        if (hist[i]) atomicAdd(&bcnt[i], hist[i]);
}

// ---------------- bucket scan (parallel) ----------------
__global__ __launch_bounds__(512) void scan_buckets(
    const int* __restrict__ bcnt, int* __restrict__ bo,
    int* __restrict__ bcur, int nb) {
    __shared__ int t0[512];
    int tid = threadIdx.x;
    int v = (tid < nb) ? bcnt[tid] : 0;
    t0[tid] = v;
    __syncthreads();
    for (int d = 1; d < 512; d <<= 1) {
        int t = (tid >= d) ? t0[tid - d] : 0;
        __syncthreads();
        t0[tid] += t;
        __syncthreads();
    }
    int ex = t0[tid] - v;
    if (tid < nb) { bo[tid] = ex; bcur[tid] = ex; }
    if (tid == 511) bo[nb] = t0[511];
}

// ---------------- partition: bucket-grouped packed edges ----------------
// 512 thr x 16 edges = 8192/chunk. Pack: src (17b) | dstlo (9b) << 17.
__global__ __launch_bounds__(512) void partition_k(
    const void* __restrict__ ei, int* __restrict__ bcur,
    unsigned* __restrict__ ep, const int* __restrict__ flags,
    int nn, int ne, int nb) {
    __shared__ unsigned stage[CHUNK];    // 32 KB
    __shared__ u16 ab[CHUNK];            // 16 KB
    __shared__ int hist[512], incl[512], exl[512], gbase[512], lcur[512];
    int tid = threadIdx.x;
    int base = blockIdx.x * CHUNK;
    hist[tid] = 0;
    __syncthreads();
    int e64 = flags[7];
    unsigned pk[16]; int bk[16];
#pragma unroll
    for (int j = 0; j < 16; j++) {
        int e = base + j * 512 + tid;
        bk[j] = -1;
        pk[j] = 0;
        if (e < ne) {
            int src, dst;
            if (e64) {
                src = (int)((const long long*)ei)[e];
                dst = (int)((const long long*)ei)[(size_t)ne + e];
            } else {
                src = ((const int*)ei)[e];
                dst = ((const int*)ei)[(size_t)ne + e];
            }
            if ((unsigned)dst < (unsigned)nn) {
                if ((unsigned)src >= (unsigned)nn) src = 0;
                bk[j] = dst >> BSHIFT;
                pk[j] = (unsigned)src | ((unsigned)(dst & (BSIZE - 1)) << 17);
                atomicAdd(&hist[bk[j]], 1);
            }
        }
    }
    __syncthreads();
    incl[tid] = hist[tid];
    __syncthreads();
    for (int d = 1; d < 512; d <<= 1) {
        int t = (tid >= d) ? incl[tid - d] : 0;
        __syncthreads();
        incl[tid] += t;
        __syncthreads();
    }
    int ex = incl[tid] - hist[tid];
    exl[tid] = ex;
    lcur[tid] = ex;
    gbase[tid] = hist[tid] ? atomicAdd(&bcur[tid], hist[tid]) : 0;
    __syncthreads();
#pragma unroll
    for (int j = 0; j < 16; j++) {
        if (bk[j] >= 0) {
            int r = atomicAdd(&lcur[bk[j]], 1);
            stage[r] = pk[j];
            ab[r] = (u16)bk[j];
        }
    }
    __syncthreads();
    int tot = incl[511];
    for (int j = tid; j < tot; j += 512) {
        int b = ab[j];
        ep[gbase[b] + (j - exl[b])] = stage[j];
    }
}

// ---------------- per-bucket CSR finalize ----------------
__global__ __launch_bounds__(512) void csr_fill2(
    const unsigned* __restrict__ ep, const int* __restrict__ bo,
    int* __restrict__ off, int* __restrict__ cnt, int* __restrict__ esrc,
    int nn) {
    __shared__ int hist[BSIZE], incl[BSIZE], lcur[BSIZE];
    int b = blockIdx.x;
    int beg = bo[b], end = bo[b + 1];
    int tid = threadIdx.x;
    hist[tid] = 0;
    __syncthreads();
    for (int j = beg + tid; j < end; j += 512)
        atomicAdd(&hist[(ep[j] >> 17) & (BSIZE - 1)], 1);
    __syncthreads();
    incl[tid] = hist[tid];
    __syncthreads();
    for (int d = 1; d < 512; d <<= 1) {
        int t = (tid >= d) ? incl[tid - d] : 0;
        __syncthreads();
        incl[tid] += t;
        __syncthreads();
    }
    int ex = beg + incl[tid] - hist[tid];
    lcur[tid] = ex;
    int node = b * BSIZE + tid;
    if (node < nn) { off[node] = ex; cnt[node] = hist[tid]; }
    __syncthreads();
    for (int j = beg + tid; j < end; j += 512) {
        unsigned p = ep[j];
        int r = atomicAdd(&lcur[(p >> 17) & (BSIZE - 1)], 1);
        esrc[r] = (int)(p & 0x1FFFFu);
    }
}

// ---------------- layer 1 ----------------
// 512 thr = 32 nodes x 16 lanes (gather) = 8 waves (MFMA).
// Tile M=32,N=128,K=128. Fragment-major LDS: chunk(tile,kc)=1KB, lane-contig.
// A element (m,k): mtile=m>>4,l15=m&15,k8=k>>3,kc=k8>>2,q=k8&3,w=k&7
//   idx = (mtile*4+kc)*512 + (q*16+l15)*8 + w        (u16 units)
// B element (n,k): same with ntile=n>>4.
__global__ __launch_bounds__(512, 4) void layer1(
    const void* __restrict__ x, const int* __restrict__ esrc,
    const int* __restrict__ off, const int* __restrict__ cnt,
    const void* __restrict__ W1l, const void* __restrict__ W1r,
    const void* __restrict__ b1, u16* __restrict__ h,
    const int* __restrict__ flags, int nn) {
    __shared__ __align__(16) u16 wB[32 * 512];   // 32 KB, chunks (ntile*4+kc)
    __shared__ __align__(16) u16 wA[8 * 512];    // 8 KB,  chunks (mtile*4+kc)
    __shared__ float b_s[128];
    int tid = threadIdx.x;
    int node0 = blockIdx.x * 32;
    int xbf = flags[0];

    // ---- stage W1l (k 0..63) / W1r (k 64..127), [64][128] row-major ----
    if (flags[1]) {
        const ushort4* s = (const ushort4*)W1l;
        for (int i = tid; i < 2048; i += 512) {
            ushort4 v = s[i]; int k = i >> 5, n = (i & 31) * 4;
            int k8 = k >> 3, kc = k8 >> 2, q = k8 & 3, w = k & 7;
            int base = ((n >> 4) * 4 + kc) * 512 + (q * 16 + (n & 15)) * 8 + w;
            wB[base] = v.x; wB[base + 8] = v.y; wB[base + 16] = v.z; wB[base + 24] = v.w;
        }
    } else {
        const float4* s = (const float4*)W1l;
        for (int i = tid; i < 2048; i += 512) {
            float4 f = s[i]; int k = i >> 5, n = (i & 31) * 4;
            int k8 = k >> 3, kc = k8 >> 2, q = k8 & 3, w = k & 7;
            int base = ((n >> 4) * 4 + kc) * 512 + (q * 16 + (n & 15)) * 8 + w;
            wB[base] = f2bf(f.x); wB[base + 8] = f2bf(f.y);
            wB[base + 16] = f2bf(f.z); wB[base + 24] = f2bf(f.w);
        }
    }
    if (flags[2]) {
        const ushort4* s = (const ushort4*)W1r;
        for (int i = tid; i < 2048; i += 512) {
            ushort4 v = s[i]; int k = i >> 5, n = (i & 31) * 4;
            int k8g = 8 + (k >> 3), kc = k8g >> 2, q = k8g & 3, w = k & 7;
            int base = ((n >> 4) * 4 + kc) * 512 + (q * 16 + (n & 15)) * 8 + w;
            wB[base] = v.x; wB[base + 8] = v.y; wB[base + 16] = v.z; wB[base + 24] = v.w;
        }
    } else {
        const float4* s = (const float4*)W1r;
        for (int i = tid; i < 2048; i += 512) {
            float4 f = s[i]; int k = i >> 5, n = (i & 31) * 4;
            int k8g = 8 + (k >> 3), kc = k8g >> 2, q = k8g & 3, w = k & 7;
            int base = ((n >> 4) * 4 + kc) * 512 + (q * 16 + (n & 15)) * 8 + w;
            wB[base] = f2bf(f.x); wB[base + 8] = f2bf(f.y);
            wB[base + 16] = f2bf(f.z); wB[base + 24] = f2bf(f.w);
        }
    }
    if (tid < 128) b_s[tid] = flags[3] ? bf2f(((const u16*)b1)[tid]) : ((const float*)b1)[tid];

    // ---- gather-mean (16 lanes/node, 4 feats/lane, unroll x8) ----
    int grp = tid >> 4, gl = tid & 15;
    int n = node0 + grp;
    int mtile = grp >> 4, l15m = grp & 15;
    // mean at k = gl*4: k8=gl>>1, kc=gl>>3, q=(gl>>1)&3, w0=(gl&1)*4
    int idx_mean = (mtile * 4 + (gl >> 3)) * 512 + (((gl >> 1) & 3) * 16 + l15m) * 8 + (gl & 1) * 4;
    // x at k = 64+gl*4: kc = 2+(gl>>3)
    int idx_x = (mtile * 4 + 2 + (gl >> 3)) * 512 + (((gl >> 1) & 3) * 16 + l15m) * 8 + (gl & 1) * 4;
    if (n < nn) {
        int beg = off[n], deg = cnt[n];
        float a0 = 0.f, a1 = 0.f, a2 = 0.f, a3 = 0.f;
        int i = 0;
        if (xbf) {
            const u16* xb = (const u16*)x + gl * 4;
            for (; i + 8 <= deg; i += 8) {
                ushort4 v[8];
#pragma unroll
                for (int j = 0; j < 8; j++) {
                    int s0 = esrc[beg + i + j];
                    v[j] = *(const ushort4*)(xb + (size_t)s0 * 64);
                }
#pragma unroll
                for (int j = 0; j < 8; j++) {
                    a0 += bf2f(v[j].x); a1 += bf2f(v[j].y);
                    a2 += bf2f(v[j].z); a3 += bf2f(v[j].w);
                }
            }
            for (; i < deg; i++) {
                int s0 = esrc[beg + i];
                ushort4 v = *(const ushort4*)(xb + (size_t)s0 * 64);
                a0 += bf2f(v.x); a1 += bf2f(v.y); a2 += bf2f(v.z); a3 += bf2f(v.w);
            }
        } else {
            const float* xb = (const float*)x + gl * 4;
            for (; i + 8 <= deg; i += 8) {
                float4 v[8];
#pragma unroll
                for (int j = 0; j < 8; j++) {
                    int s0 = esrc[beg + i + j];
                    v[j] = *(const float4*)(xb + (size_t)s0 * 64);
                }
#pragma unroll
                for (int j = 0; j < 8; j++) {
                    a0 += v[j].x; a1 += v[j].y; a2 += v[j].z; a3 += v[j].w;
                }
            }
            for (; i < deg; i++) {
                int s0 = esrc[beg + i];
                float4 v = *(const float4*)(xb + (size_t)s0 * 64);
                a0 += v.x; a1 += v.y; a2 += v.z; a3 += v.w;
            }
        }
        float inv = 1.0f / (float)(deg > 0 ? deg : 1);
        *(ushort4*)&wA[idx_mean] =
            make_ushort4(f2bf(a0 * inv), f2bf(a1 * inv), f2bf(a2 * inv), f2bf(a3 * inv));
        if (xbf) {
            *(ushort4*)&wA[idx_x] =
                *(const ushort4*)((const u16*)x + (size_t)n * 64 + gl * 4);
        } else {
            float4 xv = *(const float4*)((const float*)x + (size_t)n * 64 + gl * 4);
            *(ushort4*)&wA[idx_x] =
                make_ushort4(f2bf(xv.x), f2bf(xv.y), f2bf(xv.z), f2bf(xv.w));
        }
    } else {
        *(ushort4*)&wA[idx_mean] = make_ushort4(0, 0, 0, 0);
        *(ushort4*)&wA[idx_x] = make_ushort4(0, 0, 0, 0);
    }
    __syncthreads();

    // ---- MFMA: wave w -> ntile=w, both mtiles ----
    int wv = tid >> 6, lane = tid & 63;
    int l15 = lane & 15, q = lane >> 4;
    f32x4 acc0 = {0.f, 0.f, 0.f, 0.f};
    f32x4 acc1 = {0.f, 0.f, 0.f, 0.f};
#pragma unroll
    for (int kc = 0; kc < 4; kc++) {
        short8 a0 = *(const short8*)&wA[(kc) * 512 + lane * 8];
        short8 a1 = *(const short8*)&wA[(4 + kc) * 512 + lane * 8];
        short8 b  = *(const short8*)&wB[(wv * 4 + kc) * 512 + lane * 8];
        acc0 = __builtin_amdgcn_mfma_f32_16x16x32_bf16(a0, b, acc0, 0, 0, 0);
        acc1 = __builtin_amdgcn_mfma_f32_16x16x32_bf16(a1, b, acc1, 0, 0, 0);
    }
    int nc = wv * 16 + l15;
    float bias = b_s[nc];
#pragma unroll
    for (int r = 0; r < 4; r++) {
        int m = q * 4 + r;
        int nd = node0 + m;
        if (nd < nn) h[(size_t)nd * 128 + nc] = f2bf(fmaxf(acc0[r] + bias, 0.0f));
        nd = node0 + 16 + m;
        if (nd < nn) h[(size_t)nd * 128 + nc] = f2bf(fmaxf(acc1[r] + bias, 0.0f));
    }
}

// ---------------- layer 2 ----------------
// Tile M=32,N=64,K=256. Fragment-major LDS; chunk(tile,kc)=1KB.
// idx = (tile*8+kc)*512 + (q*16+l15)*8 + w
__global__ __launch_bounds__(512, 4) void layer2(
    const u16* __restrict__ h, const int* __restrict__ esrc,
    const int* __restrict__ off, const int* __restrict__ cnt,
    const void* __restrict__ W2l, const void* __restrict__ W2r,
    const void* __restrict__ b2, void* __restrict__ out,
    const int* __restrict__ flags, int nn) {
    __shared__ __align__(16) u16 wB2[32 * 512];  // 32 KB, (ntile*8+kc)
    __shared__ __align__(16) u16 wA2[16 * 512];  // 16 KB, (mtile*8+kc)
    __shared__ float b_s[64];
    int tid = threadIdx.x;
    int node0 = blockIdx.x * 32;
    int obf = flags[0];

    // ---- stage W2l (k 0..127) / W2r (k 128..255), [128][64] row-major ----
    if (flags[4]) {
        const ushort4* s = (const ushort4*)W2l;
        for (int i = tid; i < 2048; i += 512) {
            ushort4 v = s[i]; int k = i >> 4, n = (i & 15) * 4;
            int k8 = k >> 3, kc = k8 >> 2, q = k8 & 3, w = k & 7;
            int base = ((n >> 4) * 8 + kc) * 512 + (q * 16 + (n & 15)) * 8 + w;
            wB2[base] = v.x; wB2[base + 8] = v.y; wB2[base + 16] = v.z; wB2[base + 24] = v.w;
        }
    } else {
        const float4* s = (const float4*)W2l;
        for (int i = tid; i < 2048; i += 512) {
            float4 f = s[i]; int k = i >> 4, n = (i & 15) * 4;
            int k8 = k >> 3, kc = k8 >> 2, q = k8 & 3, w = k & 7;
            int base = ((n >> 4) * 8 + kc) * 512 + (q * 16 + (n & 15)) * 8 + w;
            wB2[base] = f2bf(f.x); wB2[base + 8] = f2bf(f.y);
            wB2[base + 16] = f2bf(f.z); wB2[base + 24] = f2bf(f.w);
        }
    }
    if (flags[5]) {
        const ushort4* s = (const ushort4*)W2r;
        for (int i = tid; i < 2048; i += 512) {
            ushort4 v = s[i]; int k = i >> 4, n = (i & 15) * 4;
            int k8g = 16 + (k >> 3), kc = k8g >> 2, q = k8g & 3, w = k & 7;
            int base = ((n >> 4) * 8 + kc) * 512 + (q * 16 + (n & 15)) * 8 + w;
            wB2[base] = v.x; wB2[base + 8] = v.y; wB2[base + 16] = v.z; wB2[base + 24] = v.w;
        }
    } else {
        const float4* s = (const float4*)W2r;
        for (int i = tid; i < 2048; i += 512) {
            float4 f = s[i]; int k = i >> 4, n = (i & 15) * 4;
            int k8g = 16 + (k >> 3), kc = k8g >> 2, q = k8g & 3, w = k & 7;
            int base = ((n >> 4) * 8 + kc) * 512 + (q * 16 + (n & 15)) * 8 + w;
            wB2[base] = f2bf(f.x); wB2[base + 8] = f2bf(f.y);
            wB2[base + 16] = f2bf(f.z); wB2[base + 24] = f2bf(f.w);
        }
    }
    if (tid < 64) b_s[tid] = flags[6] ? bf2f(((const u16*)b2)[tid]) : ((const float*)b2)[tid];

    // ---- gather-mean (16 lanes/node, 8 feats/lane, unroll x8) ----
    int grp = tid >> 4, gl = tid & 15;
    int n = node0 + grp;
    int mtile = grp >> 4, l15m = grp & 15;
    // mean at k=gl*8: k8=gl, kc=gl>>2, q=gl&3
    int idx_mean = (mtile * 8 + (gl >> 2)) * 512 + ((gl & 3) * 16 + l15m) * 8;
    // h at k=128+gl*8: kc=4+(gl>>2)
    int idx_h = (mtile * 8 + 4 + (gl >> 2)) * 512 + ((gl & 3) * 16 + l15m) * 8;
    if (n < nn) {
        int beg = off[n], deg = cnt[n];
        float a[8];
#pragma unroll
        for (int j = 0; j < 8; j++) a[j] = 0.0f;
        const u16* hb = h + (size_t)gl * 8;
        int i = 0;
        for (; i + 8 <= deg; i += 8) {
            uint4 v[8];
#pragma unroll
            for (int j = 0; j < 8; j++) {
                int s0 = esrc[beg + i + j];
                v[j] = *(const uint4*)(hb + (size_t)s0 * 128);
            }
#pragma unroll
            for (int j = 0; j < 8; j++) {
                a[0] += bfu_lo(v[j].x); a[1] += bfu_hi(v[j].x);
                a[2] += bfu_lo(v[j].y); a[3] += bfu_hi(v[j].y);
                a[4] += bfu_lo(v[j].z); a[5] += bfu_hi(v[j].z);
                a[6] += bfu_lo(v[j].w); a[7] += bfu_hi(v[j].w);
            }
        }
        for (; i < deg; i++) {
            int s0 = esrc[beg + i];
            uint4 v = *(const uint4*)(hb + (size_t)s0 * 128);
            a[0] += bfu_lo(v.x); a[1] += bfu_hi(v.x);
            a[2] += bfu_lo(v.y); a[3] += bfu_hi(v.y);
            a[4] += bfu_lo(v.z); a[5] += bfu_hi(v.z);
            a[6] += bfu_lo(v.w); a[7] += bfu_hi(v.w);
        }
        float inv = 1.0f / (float)(deg > 0 ? deg : 1);
        *(ushort4*)&wA2[idx_mean] =
            make_ushort4(f2bf(a[0] * inv), f2bf(a[1] * inv), f2bf(a[2] * inv), f2bf(a[3] * inv));
        *(ushort4*)&wA2[idx_mean + 4] =
            make_ushort4(f2bf(a[4] * inv), f2bf(a[5] * inv), f2bf(a[6] * inv), f2bf(a[7] * inv));
        uint4 hv = *(const uint4*)(h + (size_t)n * 128 + gl * 8);
        *(uint4*)&wA2[idx_h] = hv;
    } else {
        *(ushort4*)&wA2[idx_mean] = make_ushort4(0, 0, 0, 0);
        *(ushort4*)&wA2[idx_mean + 4] = make_ushort4(0, 0, 0, 0);
        *(uint4*)&wA2[idx_h] = make_uint4(0, 0, 0, 0);
    }
    __syncthreads();

    // ---- MFMA: wave w -> mtile=w>>2, ntile=w&3 ----
    int wv = tid >> 6, lane = tid & 63;
    int l15 = lane & 15, q = lane >> 4;
    int mt = wv >> 2, nt = wv & 3;
    f32x4 acc = {0.f, 0.f, 0.f, 0.f};
#pragma unroll
    for (int kc = 0; kc < 8; kc++) {
        short8 a = *(const short8*)&wA2[(mt * 8 + kc) * 512 + lane * 8];
        short8 b = *(const short8*)&wB2[(nt * 8 + kc) * 512 + lane * 8];
        acc = __builtin_amdgcn_mfma_f32_16x16x32_bf16(a, b, acc, 0, 0, 0);
    }
    int nc = nt * 16 + l15;
    float bias = b_s[nc];
#pragma unroll
    for (int r = 0; r < 4; r++) {
        int m = q * 4 + r;
        int nd = node0 + mt * 16 + m;
        if (nd < nn) {
            float v = acc[r] + bias;
            if (obf) ((u16*)out)[(size_t)nd * 64 + nc] = f2bf(v);
            else     ((float*)out)[(size_t)nd * 64 + nc] = v;
        }
    }
}

// ---------------- fallback ----------------
__global__ __launch_bounds__(256) void zero_out_k(u16* __restrict__ out, int n) {
    int i = blockIdx.x * 256 + threadIdx.x;
    if (i < n) out[i] = 0;
}

extern "C" void kernel_launch(void* const* d_in, const int* in_sizes, int n_in,
                              void* d_out, int out_size, void* d_ws, size_t ws_size,
                              hipStream_t stream) {
    const void* x   = d_in[0];
    const void* ei  = d_in[1];
    const void* W1l = d_in[2];
    const void* W1r = d_in[3];
    const void* b1  = d_in[4];
    const void* W2l = d_in[5];
    const void* W2r = d_in[6];
    const void* b2  = d_in[7];

    int nn = in_sizes[0] / 64;
    int ne = in_sizes[1] / 2;
    int nb = (nn + BSIZE - 1) / BSIZE;

    auto al = [](size_t v) { return (v + 255) & ~(size_t)255; };
    size_t o_flags = 0;
    size_t o_bcnt  = 256;
    size_t o_bo    = al(o_bcnt + 512 * 4);
    size_t o_bcur  = al(o_bo + 513 * 4);
    size_t o_cnt   = al(o_bcur + 512 * 4);
    size_t o_off   = al(o_cnt + (size_t)nn * 4);
    size_t o_esrc  = al(o_off + (size_t)nn * 4);
    size_t o_h     = al(o_esrc + (size_t)ne * 4);
    size_t ws_req  = o_h + (size_t)nn * 128 * 2;

    // ep (packed edges, ne*4 B) aliases the h region (h written after csr_fill2)
    bool ok = ws_size >= ws_req && nb >= 1 && nb <= 512 && nn <= 131072 &&
              (size_t)ne * 4 <= (size_t)nn * 256;
    if (!ok) {
        zero_out_k<<<(out_size + 255) / 256, 256, 0, stream>>>((u16*)d_out, out_size);
        return;
    }

    char* ws = (char*)d_ws;
    int* flags = (int*)(ws + o_flags);
    int* bcnt  = (int*)(ws + o_bcnt);
    int* bo    = (int*)(ws + o_bo);
    int* bcur  = (int*)(ws + o_bcur);
    int* cnt   = (int*)(ws + o_cnt);
    int* off   = (int*)(ws + o_off);
    int* esrc  = (int*)(ws + o_esrc);
    u16* h     = (u16*)(ws + o_h);
    unsigned* ep = (unsigned*)(ws + o_h);

    probe_k<<<1, 256, 0, stream>>>(x, W1l, W1r, b1, W2l, W2r, b2, ei, flags, ne,
                                   in_sizes[0], in_sizes[2], in_sizes[3], in_sizes[4],
                                   in_sizes[5], in_sizes[6], in_sizes[7]);
    hipMemsetAsync(bcnt, 0, 512 * 4, stream);
    bucket_count<<<512, 256, 0, stream>>>(ei, bcnt, flags, nn, ne, nb);
    scan_buckets<<<1, 512, 0, stream>>>(bcnt, bo, bcur, nb);
    int nchunk = (ne + CHUNK - 1) / CHUNK;
    partition_k<<<nchunk, 512, 0, stream>>>(ei, bcur, ep, flags, nn, ne, nb);
    csr_fill2<<<nb, 512, 0, stream>>>(ep, bo, off, cnt, esrc, nn);
    int lb = (nn + 31) / 32;
    layer1<<<lb, 512, 0, stream>>>(x, esrc, off, cnt, W1l, W1r, b1, h, flags, nn);
    layer2<<<lb, 512, 0, stream>>>(h, esrc, off, cnt, W2l, W2r, b2, d_out, flags, nn);
}